// Round 1
// baseline (16634.779 us; speedup 1.0000x reference)
//
#include <hip/hip_runtime.h>

// ---------------------------------------------------------------------------
// RNN seq2seq (2-layer Elman, enc 512 + dec 512, B=128, H=D=1024) + linear +
// log_softmax.
//
// Structure:
//   1) gemm_bias: pre0_enc[t,b,:] = X[t,b]@Wih0_e^T + bih0_e + bhh0_e   (f16)
//   2) rnn_phase (persistent, 256 WG = 1/CU): 513 macro-steps, skewed
//      pipeline: at step s compute h0[s] and h1[s-1]  -> 1 barrier/step
//   3) gemm_bias: pre0_dec from [X[512], Y[0..510]]
//   4) rnn_phase decoder, writes tops (f16)
//   5) gemm_bias: logits = tops@lin_W^T + lin_b  (f32 -> d_out)
//   6) logsoftmax_rows in-place on d_out
// ---------------------------------------------------------------------------

typedef _Float16 f16;
typedef _Float16 f16x8 __attribute__((ext_vector_type(8)));
typedef _Float16 f16x4 __attribute__((ext_vector_type(4)));
typedef float    f32x4 __attribute__((ext_vector_type(4)));

#define MFMA16(a, b, c) __builtin_amdgcn_mfma_f32_16x16x32_f16((a), (b), (c), 0, 0, 0)

__device__ __forceinline__ f32x4 zero4() {
  f32x4 v; v[0] = 0.f; v[1] = 0.f; v[2] = 0.f; v[3] = 0.f; return v;
}

__device__ __forceinline__ f16x8 cvt8(const float* __restrict__ p) {
  float4 a = *(const float4*)p;
  float4 b = *(const float4*)(p + 4);
  f16x8 r;
  r[0] = (f16)a.x; r[1] = (f16)a.y; r[2] = (f16)a.z; r[3] = (f16)a.w;
  r[4] = (f16)b.x; r[5] = (f16)b.y; r[6] = (f16)b.z; r[7] = (f16)b.w;
  return r;
}

// ---------------------------------------------------------------------------
// GEMM: out[m][n] = sum_k A[m][k] * B[n][k] + bias1[n] (+ bias2[n])
// A rows < rowSplit from A1, >= rowSplit from A2 (dec input concat trick).
// Tile 128x128, BK=64, 4 waves (2x2 of 64x64), reg-prefetch, 1 LDS buffer.
// LDS rows are 128B wide, XOR-swizzled with ((row&7)<<3) f16-granules so the
// 16-lane stride-2048B fragment reads are ~conflict-free.
// ---------------------------------------------------------------------------
template <typename AT, bool OUT_F16>
__global__ __launch_bounds__(256)
void gemm_bias(const AT* __restrict__ A1, const AT* __restrict__ A2, int rowSplit,
               const float* __restrict__ B, const float* __restrict__ bias1,
               const float* __restrict__ bias2, void* __restrict__ outp,
               int M, int N, int K)
{
  __shared__ f16 Ash[128 * 64];
  __shared__ f16 Bsh[128 * 64];
  const int t = threadIdx.x;
  const int w = t >> 6, l = t & 63;
  const int wm = w >> 1, wn = w & 1;
  const int lrow = l & 15, lk8 = (l >> 4) * 8;
  const int m0 = blockIdx.y * 128, n0 = blockIdx.x * 128;
  const int sr = t >> 3;         // staging row within 32-row group
  const int skf = (t & 7) * 8;   // staging k offset (8 f16 per load)

  f32x4 acc[4][4];
#pragma unroll
  for (int i = 0; i < 4; ++i)
#pragma unroll
    for (int j = 0; j < 4; ++j) acc[i][j] = zero4();

  f16x8 ar[4], br[4];

  auto loadA = [&](int r, int k) -> f16x8 {
    const int row = m0 + r;
    if constexpr (sizeof(AT) == 4) {
      const float* src = (row < rowSplit) ? ((const float*)A1 + (size_t)row * K)
                                          : ((const float*)A2 + (size_t)(row - rowSplit) * K);
      return cvt8(src + k);
    } else {
      const f16* src = (row < rowSplit) ? ((const f16*)A1 + (size_t)row * K)
                                        : ((const f16*)A2 + (size_t)(row - rowSplit) * K);
      return *(const f16x8*)(src + k);
    }
  };
  auto loadB = [&](int r, int k) -> f16x8 {
    return cvt8(B + (size_t)(n0 + r) * K + k);
  };

#pragma unroll
  for (int s = 0; s < 4; ++s) { ar[s] = loadA(s * 32 + sr, skf); br[s] = loadB(s * 32 + sr, skf); }

  const int nkt = K >> 6;
  for (int kt = 0; kt < nkt; ++kt) {
#pragma unroll
    for (int s = 0; s < 4; ++s) {
      const int r = s * 32 + sr;
      const int di = r * 64 + (skf ^ ((r & 7) << 3));
      *(f16x8*)(Ash + di) = ar[s];
      *(f16x8*)(Bsh + di) = br[s];
    }
    __syncthreads();
    if (kt + 1 < nkt) {
      const int k0 = (kt + 1) << 6;
#pragma unroll
      for (int s = 0; s < 4; ++s) { ar[s] = loadA(s * 32 + sr, k0 + skf); br[s] = loadB(s * 32 + sr, k0 + skf); }
    }
#pragma unroll
    for (int ks = 0; ks < 2; ++ks) {
      const int kb = ks * 32 + lk8;
      f16x8 af[4], bf[4];
#pragma unroll
      for (int mt = 0; mt < 4; ++mt) {
        const int r = wm * 64 + mt * 16 + lrow;
        af[mt] = *(const f16x8*)(Ash + r * 64 + (kb ^ ((r & 7) << 3)));
      }
#pragma unroll
      for (int nt = 0; nt < 4; ++nt) {
        const int r = wn * 64 + nt * 16 + lrow;
        bf[nt] = *(const f16x8*)(Bsh + r * 64 + (kb ^ ((r & 7) << 3)));
      }
#pragma unroll
      for (int mt = 0; mt < 4; ++mt)
#pragma unroll
        for (int nt = 0; nt < 4; ++nt)
          acc[mt][nt] = MFMA16(af[mt], bf[nt], acc[mt][nt]);
    }
    __syncthreads();
  }

#pragma unroll
  for (int nt = 0; nt < 4; ++nt) {
    const int col = n0 + wn * 64 + nt * 16 + lrow;
    const float bv = bias1[col] + (bias2 ? bias2[col] : 0.f);
#pragma unroll
    for (int mt = 0; mt < 4; ++mt) {
#pragma unroll
      for (int r = 0; r < 4; ++r) {
        const int row = m0 + wm * 64 + mt * 16 + (l >> 4) * 4 + r;
        const float v = acc[mt][nt][r] + bv;
        if constexpr (OUT_F16) ((f16*)outp)[(size_t)row * N + col] = (f16)v;
        else                   ((float*)outp)[(size_t)row * N + col] = v;
      }
    }
  }
}

// ---------------------------------------------------------------------------
// Persistent RNN phase. Grid = 256 blocks x 256 threads (1 block/CU forced by
// 112KB LDS -> all co-resident). Block bid: group g = bid&3 (batch rows
// g*32..g*32+31), slice = bid>>2 (h0 cols [slice*16,+16) and h1 cols same).
// Weight slices (3 x 16x1024 f16) live in LDS for the whole phase.
// Macro-step s (s_loc 0..512): h0[s] = tanh(pre0[s] + h0[s-1]@Whh0^T) and
// h1[s-1] = tanh(h0[s-1]@Wih1^T + h1[s-2]@Whh1^T + b1). Hidden state is f16
// triple-buffered in global; one per-group barrier per step (monotonic
// counter, release-add / relaxed-spin / acquire-fence).
// Buffer indices: R0=(s+2)%3 W0=s%3 ; R1=(s+1)%3 W1=(s+2)%3 (of h1 array).
// s_loc==512: copy-through h0 (keeps rotation valid across the enc->dec
// launch boundary). Dec s_loc==0: copy-through h1 for the same reason.
// ---------------------------------------------------------------------------
#define RNN_LDS (3 * 16 * 1024 * 2 + 64 + 4 * 2 * 32 * 16 * 4)

__global__ __launch_bounds__(256)
void rnn_phase(const f16* __restrict__ pre0,          // [512][128][1024]
               f16* __restrict__ h0b,                 // [3][128][1024]
               f16* __restrict__ h1b,                 // [3][128][1024]
               unsigned* __restrict__ cnt,            // 4 counters, 256B apart
               const float* __restrict__ Whh0, const float* __restrict__ Wih1,
               const float* __restrict__ Whh1, const float* __restrict__ bih1,
               const float* __restrict__ bhh1,
               f16* __restrict__ tops,                // [512][128][1024] or null
               int s_base)
{
  extern __shared__ char smem[];
  f16* W0s = (f16*)smem;               // Whh0 slice [16][1024]
  f16* W1s = W0s + 16 * 1024;          // Wih1 slice
  f16* W2s = W1s + 16 * 1024;          // Whh1 slice
  float* b1s = (float*)(W2s + 16 * 1024);   // 16 floats
  float* pbuf = b1s + 16;              // [4 waves][2 parts][32 rows][16 cols] f32

  const int t = threadIdx.x;
  const int w = t >> 6, l = t & 63;
  const int lrow = l & 15, lk8 = (l >> 4) * 8;
  const int bid = blockIdx.x;
  const int g = bid & 3;
  const int slice = bid >> 2;
  const int c0 = slice * 16;
  const int rbase = g * 32;
  const bool is_dec = (s_base != 0);

  // ---- stage weight slices f32 -> f16 into LDS (XOR-swizzled rows) ----
  {
    const int r = t >> 4;              // 0..15 (local weight row = out col)
    const int kb = (t & 15) * 64;
    const float* s0 = Whh0 + (size_t)(c0 + r) * 1024;
    const float* s1 = Wih1 + (size_t)(c0 + r) * 1024;
    const float* s2 = Whh1 + (size_t)(c0 + r) * 1024;
#pragma unroll
    for (int i = 0; i < 8; ++i) {
      const int k = kb + i * 8;
      const int di = r * 1024 + (k ^ ((r & 7) << 3));
      *(f16x8*)(W0s + di) = cvt8(s0 + k);
      *(f16x8*)(W1s + di) = cvt8(s1 + k);
      *(f16x8*)(W2s + di) = cvt8(s2 + k);
    }
  }
  if (t < 16) b1s[t] = bih1[c0 + t] + bhh1[c0 + t];
  __syncthreads();

  unsigned* mycnt = cnt + g * 64;      // 256B apart

  // epilogue thread mapping: 128 threads per part, 4 outputs each
  const int ep_p = t >> 7;             // 0: h0 part, 1: h1 part
  const int ep_r = (t >> 2) & 31;      // local row 0..31
  const int ep_c = (t & 3) * 4;        // local col chunk

  for (int s_loc = 0; s_loc <= 512; ++s_loc) {
    const int s = s_base + s_loc;
    const int R0 = (s + 2) % 3, Wr0 = s % 3;
    const int R1 = (s + 1) % 3, Wr1 = (s + 2) % 3;
    const f16* h0p = h0b + (size_t)R0 * 131072;
    const f16* h1p = h1b + (size_t)R1 * 131072;
    f16* h0w = h0b + (size_t)Wr0 * 131072;
    f16* h1w = h1b + (size_t)Wr1 * 131072;
    const bool cmp_h0 = (s_loc < 512);
    const bool h1_skip = (!is_dec && s_loc == 0);
    const bool h1_copy = (is_dec && s_loc == 0);
    const bool cmp_h1 = !(h1_skip || h1_copy);

    // early pre0 load (hides L3 latency behind the MFMA section)
    f16x4 pre4;
    pre4[0] = (f16)0.f; pre4[1] = (f16)0.f; pre4[2] = (f16)0.f; pre4[3] = (f16)0.f;
    if (ep_p == 0 && cmp_h0)
      pre4 = *(const f16x4*)(pre0 + ((size_t)s_loc * 128 + rbase + ep_r) * 1024 + c0 + ep_c);

    f32x4 acc0[2], acc1[2];
    acc0[0] = zero4(); acc0[1] = zero4(); acc1[0] = zero4(); acc1[1] = zero4();

    if (cmp_h0) {                       // h0[s]: K=1024 over h0_prev, wave K-split 256
      const int kw = w * 256;
#pragma unroll
      for (int kk = 0; kk < 256; kk += 32) {
        const int k = kw + kk + lk8;
        f16x8 b  = *(const f16x8*)(W0s + lrow * 1024 + (k ^ ((lrow & 7) << 3)));
        f16x8 a0 = *(const f16x8*)(h0p + (size_t)(rbase + lrow) * 1024 + k);
        f16x8 a1 = *(const f16x8*)(h0p + (size_t)(rbase + 16 + lrow) * 1024 + k);
        acc0[0] = MFMA16(a0, b, acc0[0]);
        acc0[1] = MFMA16(a1, b, acc0[1]);
      }
    }
    if (cmp_h1) {                       // h1[s-1]: K=2048 over [h0_prev ; h1_prev2]
      const f16* src = (w < 2) ? h0p : h1p;
      const f16* Ws  = (w < 2) ? W1s : W2s;
      const int kw = (w & 1) * 512;
#pragma unroll
      for (int kk = 0; kk < 512; kk += 32) {
        const int k = kw + kk + lk8;
        f16x8 b  = *(const f16x8*)(Ws + lrow * 1024 + (k ^ ((lrow & 7) << 3)));
        f16x8 a0 = *(const f16x8*)(src + (size_t)(rbase + lrow) * 1024 + k);
        f16x8 a1 = *(const f16x8*)(src + (size_t)(rbase + 16 + lrow) * 1024 + k);
        acc1[0] = MFMA16(a0, b, acc1[0]);
        acc1[1] = MFMA16(a1, b, acc1[1]);
      }
    }

    // partials -> LDS
#pragma unroll
    for (int mt = 0; mt < 2; ++mt)
#pragma unroll
      for (int r = 0; r < 4; ++r) {
        const int row = mt * 16 + (l >> 4) * 4 + r;
        if (cmp_h0) pbuf[((w * 2 + 0) * 32 + row) * 16 + lrow] = acc0[mt][r];
        if (cmp_h1) pbuf[((w * 2 + 1) * 32 + row) * 16 + lrow] = acc1[mt][r];
      }
    __syncthreads();

    // reduce over 4 waves + activation + global store
    if (ep_p == 0) {
      if (cmp_h0) {
        f32x4 sum = zero4();
#pragma unroll
        for (int ww = 0; ww < 4; ++ww) {
          f32x4 v = *(const f32x4*)(pbuf + ((ww * 2 + 0) * 32 + ep_r) * 16 + ep_c);
          sum += v;
        }
        f16x4 o;
#pragma unroll
        for (int i = 0; i < 4; ++i) o[i] = (f16)tanhf(sum[i] + (float)pre4[i]);
        *(f16x4*)(h0w + (size_t)(rbase + ep_r) * 1024 + c0 + ep_c) = o;
      } else {                          // copy-through h0 at drain step
        f16x4 v = *(const f16x4*)(h0p + (size_t)(rbase + ep_r) * 1024 + c0 + ep_c);
        *(f16x4*)(h0w + (size_t)(rbase + ep_r) * 1024 + c0 + ep_c) = v;
      }
    } else {
      if (cmp_h1) {
        f32x4 sum = zero4();
#pragma unroll
        for (int ww = 0; ww < 4; ++ww) {
          f32x4 v = *(const f32x4*)(pbuf + ((ww * 2 + 1) * 32 + ep_r) * 16 + ep_c);
          sum += v;
        }
        f16x4 o;
#pragma unroll
        for (int i = 0; i < 4; ++i) o[i] = (f16)tanhf(sum[i] + b1s[ep_c + i]);
        *(f16x4*)(h1w + (size_t)(rbase + ep_r) * 1024 + c0 + ep_c) = o;
        if (tops && s_loc >= 1)
          *(f16x4*)(tops + ((size_t)(s_loc - 1) * 128 + rbase + ep_r) * 1024 + c0 + ep_c) = o;
      } else if (h1_copy) {             // dec fill step: carry h1_enc[511] forward
        f16x4 v = *(const f16x4*)(h1p + (size_t)(rbase + ep_r) * 1024 + c0 + ep_c);
        *(f16x4*)(h1w + (size_t)(rbase + ep_r) * 1024 + c0 + ep_c) = v;
      }
    }
    __syncthreads();                    // drains vmem before the arrive

    // ---- per-group barrier: release add, relaxed spin, acquire fence ----
    if (t == 0) {
      __hip_atomic_fetch_add(mycnt, 1u, __ATOMIC_RELEASE, __HIP_MEMORY_SCOPE_AGENT);
      const unsigned target = 64u * (unsigned)(s_loc + 1);
      while (__hip_atomic_load(mycnt, __ATOMIC_RELAXED, __HIP_MEMORY_SCOPE_AGENT) < target)
        __builtin_amdgcn_s_sleep(4);
      __builtin_amdgcn_fence(__ATOMIC_ACQUIRE, "agent");  // inv L1+L2
    }
    __syncthreads();
  }
}

// ---------------------------------------------------------------------------
// In-place log_softmax over rows of 1024 f32.
// ---------------------------------------------------------------------------
__global__ __launch_bounds__(256)
void logsoftmax_rows(float* __restrict__ x)
{
  const int row = blockIdx.x;
  const int t = threadIdx.x;
  float* p = x + (size_t)row * 1024;
  float4 v = ((float4*)p)[t];
  float m = fmaxf(fmaxf(v.x, v.y), fmaxf(v.z, v.w));
#pragma unroll
  for (int off = 32; off >= 1; off >>= 1) m = fmaxf(m, __shfl_xor(m, off));
  __shared__ float red[4];
  __shared__ float red2[4];
  const int w = t >> 6;
  if ((t & 63) == 0) red[w] = m;
  __syncthreads();
  m = fmaxf(fmaxf(red[0], red[1]), fmaxf(red[2], red[3]));
  float s = __expf(v.x - m) + __expf(v.y - m) + __expf(v.z - m) + __expf(v.w - m);
#pragma unroll
  for (int off = 32; off >= 1; off >>= 1) s += __shfl_xor(s, off);
  if ((t & 63) == 0) red2[w] = s;
  __syncthreads();
  s = red2[0] + red2[1] + red2[2] + red2[3];
  const float lse = m + __logf(s);
  v.x -= lse; v.y -= lse; v.z -= lse; v.w -= lse;
  ((float4*)p)[t] = v;
}

// ---------------------------------------------------------------------------
extern "C" void kernel_launch(void* const* d_in, const int* in_sizes, int n_in,
                              void* d_out, int out_size, void* d_ws, size_t ws_size,
                              hipStream_t stream)
{
  (void)in_sizes; (void)n_in; (void)out_size; (void)ws_size;

  const float* X    = (const float*)d_in[0];   // [513][128][1024]
  const float* Y    = (const float*)d_in[1];   // [512][128][1024]
  const float* eWih = (const float*)d_in[2];   // [2][1024][1024]
  const float* eWhh = (const float*)d_in[3];
  const float* ebih = (const float*)d_in[4];   // [2][1024]
  const float* ebhh = (const float*)d_in[5];
  const float* dWih = (const float*)d_in[6];
  const float* dWhh = (const float*)d_in[7];
  const float* dbih = (const float*)d_in[8];
  const float* dbhh = (const float*)d_in[9];
  const float* linW = (const float*)d_in[10];  // [1024][1024]
  const float* linb = (const float*)d_in[11];  // [1024]

  // workspace layout
  char* ws = (char*)d_ws;
  unsigned* cnt = (unsigned*)ws;                                  // 4KB
  f16* h0b  = (f16*)(ws + 4096);                                  // 3*128*1024*2
  f16* h1b  = (f16*)(ws + 4096 + 786432);
  f16* pre0 = (f16*)(ws + 2097152);                               // 128MB
  f16* tops = (f16*)(ws + 2097152 + 134217728);                   // 128MB

  const size_t LAYER1 = 1024 * 1024;   // offset of layer-1 weights
  const int M = 512 * 128;

  hipFuncSetAttribute((const void*)rnn_phase,
                      hipFuncAttributeMaxDynamicSharedMemorySize, RNN_LDS);

  // zero counters + hidden state
  hipMemsetAsync(d_ws, 0, 4096 + 2 * 786432, stream);

  dim3 ggrid(8, 512);  // (N/128, M/128); col-block fastest for A-panel reuse

  // 1) encoder layer-0 input GEMM
  gemm_bias<float, true><<<ggrid, 256, 0, stream>>>(
      X, X, 1 << 30, eWih, ebih, ebhh, pre0, M, 1024, 1024);

  // 2) encoder recurrence
  rnn_phase<<<256, 256, RNN_LDS, stream>>>(
      pre0, h0b, h1b, cnt,
      eWhh, eWih + LAYER1, eWhh + LAYER1, ebih + 1024, ebhh + 1024,
      nullptr, 0);

  // 3) decoder layer-0 input GEMM: rows 0..127 from X[512], rest from Y
  gemm_bias<float, true><<<ggrid, 256, 0, stream>>>(
      X + (size_t)512 * 128 * 1024, Y, 128, dWih, dbih, dbhh, pre0, M, 1024, 1024);

  // zero counters for decoder phase (hidden state carries over)
  hipMemsetAsync(d_ws, 0, 4096, stream);

  // 4) decoder recurrence (writes tops)
  rnn_phase<<<256, 256, RNN_LDS, stream>>>(
      pre0, h0b, h1b, cnt,
      dWhh, dWih + LAYER1, dWhh + LAYER1, dbih + 1024, dbhh + 1024,
      tops, 513);

  // 5) final linear -> logits (f32) into d_out
  gemm_bias<f16, false><<<ggrid, 256, 0, stream>>>(
      tops, tops, 1 << 30, linW, linb, nullptr, d_out, M, 1024, 1024);

  // 6) in-place log_softmax
  logsoftmax_rows<<<M, 256, 0, stream>>>((float*)d_out);
}

// Round 2
// 12986.269 us; speedup vs baseline: 1.2810x; 1.2810x over previous
//
#include <hip/hip_runtime.h>

// ---------------------------------------------------------------------------
// RNN seq2seq (2-layer Elman, enc 512 + dec 512, B=128, H=D=1024) + linear +
// log_softmax.
//
//   1) gemm_bias: pre0_enc = X@Wih0_e^T + b          (f16)
//   2) rnn_phase (persistent, 256 WG = 1/CU): skewed pipeline, 1 barrier/step
//   3) gemm_bias: pre0_dec from [X[512], Y[0..510]]
//   4) rnn_phase decoder, writes tops (f16)
//   5) gemm_bias: logits = tops@lin_W^T + lin_b  (f32 -> d_out)
//   6) logsoftmax_rows in-place on d_out
//
// Cross-block coherence (round 2): NO fences. All h-state exchange goes
// through relaxed agent-scope 8B atomics, which on gfx950 lower to
// global_load/store with sc1 (bypass non-coherent per-XCD L2, serialize at
// the MALL/L3). Barrier: __syncthreads drains vmcnt (stores acked at the
// coherence point), then per-block flag = step number, wave0 polls its
// group's 64 flags in parallel. No buffer_wbl2 / buffer_inv per step.
// ---------------------------------------------------------------------------

typedef _Float16 f16;
typedef _Float16 f16x8 __attribute__((ext_vector_type(8)));
typedef _Float16 f16x4 __attribute__((ext_vector_type(4)));
typedef float    f32x4 __attribute__((ext_vector_type(4)));
typedef unsigned long long u64;

#define MFMA16(a, b, c) __builtin_amdgcn_mfma_f32_16x16x32_f16((a), (b), (c), 0, 0, 0)

__device__ __forceinline__ f32x4 zero4() {
  f32x4 v; v[0] = 0.f; v[1] = 0.f; v[2] = 0.f; v[3] = 0.f; return v;
}

__device__ __forceinline__ f16x8 cvt8(const float* __restrict__ p) {
  float4 a = *(const float4*)p;
  float4 b = *(const float4*)(p + 4);
  f16x8 r;
  r[0] = (f16)a.x; r[1] = (f16)a.y; r[2] = (f16)a.z; r[3] = (f16)a.w;
  r[4] = (f16)b.x; r[5] = (f16)b.y; r[6] = (f16)b.z; r[7] = (f16)b.w;
  return r;
}

// --- agent-coherent (L2-bypassing, MALL-serialized) 8B load/store ---------
__device__ __forceinline__ f16x4 ld_h4(const f16* p) {
  u64 v = __hip_atomic_load((const u64*)p, __ATOMIC_RELAXED, __HIP_MEMORY_SCOPE_AGENT);
  return __builtin_bit_cast(f16x4, v);
}
__device__ __forceinline__ void st_h4(f16* p, f16x4 v) {
  __hip_atomic_store((u64*)p, __builtin_bit_cast(u64, v), __ATOMIC_RELAXED, __HIP_MEMORY_SCOPE_AGENT);
}
__device__ __forceinline__ f16x8 ld_h8(const f16* p) {
  u64 lo = __hip_atomic_load((const u64*)p,     __ATOMIC_RELAXED, __HIP_MEMORY_SCOPE_AGENT);
  u64 hi = __hip_atomic_load((const u64*)p + 1, __ATOMIC_RELAXED, __HIP_MEMORY_SCOPE_AGENT);
  f16x4 l4 = __builtin_bit_cast(f16x4, lo), h4 = __builtin_bit_cast(f16x4, hi);
  f16x8 r;
  r[0] = l4[0]; r[1] = l4[1]; r[2] = l4[2]; r[3] = l4[3];
  r[4] = h4[0]; r[5] = h4[1]; r[6] = h4[2]; r[7] = h4[3];
  return r;
}

// ---------------------------------------------------------------------------
// GEMM: out[m][n] = sum_k A[m][k] * B[n][k] + bias1[n] (+ bias2[n])
// ---------------------------------------------------------------------------
template <typename AT, bool OUT_F16>
__global__ __launch_bounds__(256)
void gemm_bias(const AT* __restrict__ A1, const AT* __restrict__ A2, int rowSplit,
               const float* __restrict__ B, const float* __restrict__ bias1,
               const float* __restrict__ bias2, void* __restrict__ outp,
               int M, int N, int K)
{
  __shared__ f16 Ash[128 * 64];
  __shared__ f16 Bsh[128 * 64];
  const int t = threadIdx.x;
  const int w = t >> 6, l = t & 63;
  const int wm = w >> 1, wn = w & 1;
  const int lrow = l & 15, lk8 = (l >> 4) * 8;
  const int m0 = blockIdx.y * 128, n0 = blockIdx.x * 128;
  const int sr = t >> 3;
  const int skf = (t & 7) * 8;

  f32x4 acc[4][4];
#pragma unroll
  for (int i = 0; i < 4; ++i)
#pragma unroll
    for (int j = 0; j < 4; ++j) acc[i][j] = zero4();

  f16x8 ar[4], br[4];

  auto loadA = [&](int r, int k) -> f16x8 {
    const int row = m0 + r;
    if constexpr (sizeof(AT) == 4) {
      const float* src = (row < rowSplit) ? ((const float*)A1 + (size_t)row * K)
                                          : ((const float*)A2 + (size_t)(row - rowSplit) * K);
      return cvt8(src + k);
    } else {
      const f16* src = (row < rowSplit) ? ((const f16*)A1 + (size_t)row * K)
                                        : ((const f16*)A2 + (size_t)(row - rowSplit) * K);
      return *(const f16x8*)(src + k);
    }
  };
  auto loadB = [&](int r, int k) -> f16x8 {
    return cvt8(B + (size_t)(n0 + r) * K + k);
  };

#pragma unroll
  for (int s = 0; s < 4; ++s) { ar[s] = loadA(s * 32 + sr, skf); br[s] = loadB(s * 32 + sr, skf); }

  const int nkt = K >> 6;
  for (int kt = 0; kt < nkt; ++kt) {
#pragma unroll
    for (int s = 0; s < 4; ++s) {
      const int r = s * 32 + sr;
      const int di = r * 64 + (skf ^ ((r & 7) << 3));
      *(f16x8*)(Ash + di) = ar[s];
      *(f16x8*)(Bsh + di) = br[s];
    }
    __syncthreads();
    if (kt + 1 < nkt) {
      const int k0 = (kt + 1) << 6;
#pragma unroll
      for (int s = 0; s < 4; ++s) { ar[s] = loadA(s * 32 + sr, k0 + skf); br[s] = loadB(s * 32 + sr, k0 + skf); }
    }
#pragma unroll
    for (int ks = 0; ks < 2; ++ks) {
      const int kb = ks * 32 + lk8;
      f16x8 af[4], bf[4];
#pragma unroll
      for (int mt = 0; mt < 4; ++mt) {
        const int r = wm * 64 + mt * 16 + lrow;
        af[mt] = *(const f16x8*)(Ash + r * 64 + (kb ^ ((r & 7) << 3)));
      }
#pragma unroll
      for (int nt = 0; nt < 4; ++nt) {
        const int r = wn * 64 + nt * 16 + lrow;
        bf[nt] = *(const f16x8*)(Bsh + r * 64 + (kb ^ ((r & 7) << 3)));
      }
#pragma unroll
      for (int mt = 0; mt < 4; ++mt)
#pragma unroll
        for (int nt = 0; nt < 4; ++nt)
          acc[mt][nt] = MFMA16(af[mt], bf[nt], acc[mt][nt]);
    }
    __syncthreads();
  }

#pragma unroll
  for (int nt = 0; nt < 4; ++nt) {
    const int col = n0 + wn * 64 + nt * 16 + lrow;
    const float bv = bias1[col] + (bias2 ? bias2[col] : 0.f);
#pragma unroll
    for (int mt = 0; mt < 4; ++mt) {
#pragma unroll
      for (int r = 0; r < 4; ++r) {
        const int row = m0 + wm * 64 + mt * 16 + (l >> 4) * 4 + r;
        const float v = acc[mt][nt][r] + bv;
        if constexpr (OUT_F16) ((f16*)outp)[(size_t)row * N + col] = (f16)v;
        else                   ((float*)outp)[(size_t)row * N + col] = v;
      }
    }
  }
}

// ---------------------------------------------------------------------------
// Persistent RNN phase. 256 blocks x 256 threads, 1 block/CU (118KB LDS).
// Block bid: group g = bid&3 (batch rows g*32..+31), slice = bid>>2 (out cols
// [slice*16,+16)). Weight slices (3 x 16x1024 f16) in LDS for the phase.
// Step s_loc: h0[s] = tanh(pre0[s] + h0[s-1]@Whh0^T) and
// h1[s-1] = tanh(h0[s-1]@Wih1^T + h1[s-2]@Whh1^T + b1), merged: each wave
// owns a K-quarter, loads h0 fragments ONCE for both Whh0 and Wih1 MFMAs.
// Inner loop is branch-free (boundary steps multiply by zeroed state).
// ---------------------------------------------------------------------------
#define RNN_LDS (3 * 16 * 1024 * 2 + 64 + 8 * 32 * 20 * 4)

__global__ __launch_bounds__(256)
void rnn_phase(const f16* __restrict__ pre0,          // [512][128][1024]
               f16* __restrict__ h0b,                 // [3][128][1024]
               f16* __restrict__ h1b,                 // [3][128][1024]
               unsigned* flags,                       // [256] per-block step flags
               const float* __restrict__ Whh0, const float* __restrict__ Wih1,
               const float* __restrict__ Whh1, const float* __restrict__ bih1,
               const float* __restrict__ bhh1,
               f16* __restrict__ tops,                // [512][128][1024] or null
               int s_base)
{
  extern __shared__ char smem[];
  f16* W0s = (f16*)smem;               // Whh0 slice [16][1024]
  f16* W1s = W0s + 16 * 1024;          // Wih1 slice
  f16* W2s = W1s + 16 * 1024;          // Whh1 slice
  float* b1s = (float*)(W2s + 16 * 1024);   // 16 floats
  float* pbuf = b1s + 16;              // [4 waves][2 parts][32 rows][20] f32 (padded)

  const int t = threadIdx.x;
  const int w = t >> 6, l = t & 63;
  const int lrow = l & 15, lk8 = (l >> 4) * 8;
  const int bid = blockIdx.x;
  const int g = bid & 3;
  const int rbase = g * 32;
  const int c0 = (bid >> 2) * 16;
  const bool is_dec = (s_base != 0);

  // ---- stage weight slices f32 -> f16 into LDS (XOR-swizzled rows) ----
  {
    const int r = t >> 4;              // 0..15
    const int kb = (t & 15) * 64;
    const float* s0 = Whh0 + (size_t)(c0 + r) * 1024;
    const float* s1 = Wih1 + (size_t)(c0 + r) * 1024;
    const float* s2 = Whh1 + (size_t)(c0 + r) * 1024;
#pragma unroll
    for (int i = 0; i < 8; ++i) {
      const int k = kb + i * 8;
      const int di = r * 1024 + (k ^ ((r & 7) << 3));
      *(f16x8*)(W0s + di) = cvt8(s0 + k);
      *(f16x8*)(W1s + di) = cvt8(s1 + k);
      *(f16x8*)(W2s + di) = cvt8(s2 + k);
    }
  }
  if (t < 16) b1s[t] = bih1[c0 + t] + bhh1[c0 + t];
  __syncthreads();

  // epilogue thread mapping: 128 threads per part, 4 outputs each
  const int ep_p = t >> 7;             // 0: h0 part, 1: h1 part
  const int ep_r = (t >> 2) & 31;      // local row 0..31
  const int ep_c = (t & 3) * 4;        // local col chunk

  const int kw = w * 256;              // wave K-quarter

  for (int s_loc = 0; s_loc <= 512; ++s_loc) {
    const int s = s_base + s_loc;
    const int R0 = (s + 2) % 3, Wr0 = s % 3;
    const int R1 = (s + 1) % 3, Wr1 = (s + 2) % 3;
    const f16* h0p = h0b + (size_t)R0 * 131072;
    const f16* h1p = h1b + (size_t)R1 * 131072;
    f16* h0w = h0b + (size_t)Wr0 * 131072;
    f16* h1w = h1b + (size_t)Wr1 * 131072;
    const bool cmp_h0 = (s_loc < 512);
    const bool h1_copy = (is_dec && s_loc == 0);
    const bool cmp_h1 = !((!is_dec && s_loc == 0) || h1_copy);

    // early pre0 load (plain cached; hides HBM latency behind MFMA section)
    f16x4 pre4;
    pre4[0] = (f16)0.f; pre4[1] = (f16)0.f; pre4[2] = (f16)0.f; pre4[3] = (f16)0.f;
    if (ep_p == 0 && cmp_h0)
      pre4 = *(const f16x4*)(pre0 + ((size_t)s_loc * 128 + rbase + ep_r) * 1024 + c0 + ep_c);

    f32x4 acc0[2], acc1[2];
    acc0[0] = zero4(); acc0[1] = zero4(); acc1[0] = zero4(); acc1[1] = zero4();

    // merged branch-free MFMA loop: wave K-quarter for all three matmuls
    {
      const f16* a0p = h0p + (size_t)(rbase + lrow) * 1024 + kw + lk8;
      const f16* a1p = a0p + 16 * 1024;
      const f16* c0p = h1p + (size_t)(rbase + lrow) * 1024 + kw + lk8;
      const f16* c1p = c0p + 16 * 1024;
      const int wrow = lrow * 1024;
#pragma unroll
      for (int kk = 0; kk < 256; kk += 32) {
        const int k = kw + kk + lk8;
        const int swz = wrow + (k ^ ((lrow & 7) << 3));
        f16x8 b0 = *(const f16x8*)(W0s + swz);
        f16x8 b1 = *(const f16x8*)(W1s + swz);
        f16x8 b2 = *(const f16x8*)(W2s + swz);
        f16x8 a0 = ld_h8(a0p + kk);
        f16x8 a1 = ld_h8(a1p + kk);
        f16x8 cc0 = ld_h8(c0p + kk);
        f16x8 cc1 = ld_h8(c1p + kk);
        acc0[0] = MFMA16(a0, b0, acc0[0]);  acc0[1] = MFMA16(a1, b0, acc0[1]);
        acc1[0] = MFMA16(a0, b1, acc1[0]);  acc1[1] = MFMA16(a1, b1, acc1[1]);
        acc1[0] = MFMA16(cc0, b2, acc1[0]); acc1[1] = MFMA16(cc1, b2, acc1[1]);
      }
    }

    // partials -> LDS (stride 20: conflict-free scalar writes, aligned reads)
#pragma unroll
    for (int mt = 0; mt < 2; ++mt)
#pragma unroll
      for (int r = 0; r < 4; ++r) {
        const int row = mt * 16 + (l >> 4) * 4 + r;
        pbuf[((w * 2 + 0) * 32 + row) * 20 + lrow] = acc0[mt][r];
        pbuf[((w * 2 + 1) * 32 + row) * 20 + lrow] = acc1[mt][r];
      }
    __syncthreads();

    // reduce over 4 waves + activation + agent-coherent store
    if (ep_p == 0) {
      if (cmp_h0) {
        f32x4 sum = zero4();
#pragma unroll
        for (int ww = 0; ww < 4; ++ww)
          sum += *(const f32x4*)(pbuf + ((ww * 2 + 0) * 32 + ep_r) * 20 + ep_c);
        f16x4 o;
#pragma unroll
        for (int i = 0; i < 4; ++i) o[i] = (f16)tanhf(sum[i] + (float)pre4[i]);
        st_h4(h0w + (size_t)(rbase + ep_r) * 1024 + c0 + ep_c, o);
      } else {                          // drain step: carry h0[511] forward
        f16x4 v = ld_h4(h0p + (size_t)(rbase + ep_r) * 1024 + c0 + ep_c);
        st_h4(h0w + (size_t)(rbase + ep_r) * 1024 + c0 + ep_c, v);
      }
    } else {
      if (cmp_h1) {
        f32x4 sum = zero4();
#pragma unroll
        for (int ww = 0; ww < 4; ++ww)
          sum += *(const f32x4*)(pbuf + ((ww * 2 + 1) * 32 + ep_r) * 20 + ep_c);
        f16x4 o;
#pragma unroll
        for (int i = 0; i < 4; ++i) o[i] = (f16)tanhf(sum[i] + b1s[ep_c + i]);
        st_h4(h1w + (size_t)(rbase + ep_r) * 1024 + c0 + ep_c, o);
        if (tops && s_loc >= 1)
          *(f16x4*)(tops + ((size_t)(s_loc - 1) * 128 + rbase + ep_r) * 1024 + c0 + ep_c) = o;
      } else if (h1_copy) {             // dec fill step: carry h1_enc[511]
        f16x4 v = ld_h4(h1p + (size_t)(rbase + ep_r) * 1024 + c0 + ep_c);
        st_h4(h1w + (size_t)(rbase + ep_r) * 1024 + c0 + ep_c, v);
      }
    }
    __syncthreads();                    // all waves drain vmcnt before barrier

    if (s_loc == 512) break;            // no consumer of the last step in-kernel

    // ---- fence-free group barrier through the MALL ----
    asm volatile("s_waitcnt vmcnt(0)" ::: "memory");
    if (t == 0)
      __hip_atomic_store(flags + bid, (unsigned)(s_loc + 1),
                         __ATOMIC_RELAXED, __HIP_MEMORY_SCOPE_AGENT);
    if (w == 0) {                       // wave0: poll my group's 64 flags
      unsigned* fp = flags + 4 * l + g;
      const unsigned tgt = (unsigned)(s_loc + 1);
      for (;;) {
        unsigned v = __hip_atomic_load(fp, __ATOMIC_RELAXED, __HIP_MEMORY_SCOPE_AGENT);
        if (__all((int)(v >= tgt))) break;
        __builtin_amdgcn_s_sleep(2);
      }
    }
    __syncthreads();
  }
}

// ---------------------------------------------------------------------------
// In-place log_softmax over rows of 1024 f32.
// ---------------------------------------------------------------------------
__global__ __launch_bounds__(256)
void logsoftmax_rows(float* __restrict__ x)
{
  const int row = blockIdx.x;
  const int t = threadIdx.x;
  float* p = x + (size_t)row * 1024;
  float4 v = ((float4*)p)[t];
  float m = fmaxf(fmaxf(v.x, v.y), fmaxf(v.z, v.w));
#pragma unroll
  for (int off = 32; off >= 1; off >>= 1) m = fmaxf(m, __shfl_xor(m, off));
  __shared__ float red[4];
  __shared__ float red2[4];
  const int w = t >> 6;
  if ((t & 63) == 0) red[w] = m;
  __syncthreads();
  m = fmaxf(fmaxf(red[0], red[1]), fmaxf(red[2], red[3]));
  float s = __expf(v.x - m) + __expf(v.y - m) + __expf(v.z - m) + __expf(v.w - m);
#pragma unroll
  for (int off = 32; off >= 1; off >>= 1) s += __shfl_xor(s, off);
  if ((t & 63) == 0) red2[w] = s;
  __syncthreads();
  s = red2[0] + red2[1] + red2[2] + red2[3];
  const float lse = m + __logf(s);
  v.x -= lse; v.y -= lse; v.z -= lse; v.w -= lse;
  ((float4*)p)[t] = v;
}

// ---------------------------------------------------------------------------
extern "C" void kernel_launch(void* const* d_in, const int* in_sizes, int n_in,
                              void* d_out, int out_size, void* d_ws, size_t ws_size,
                              hipStream_t stream)
{
  (void)in_sizes; (void)n_in; (void)out_size; (void)ws_size;

  const float* X    = (const float*)d_in[0];   // [513][128][1024]
  const float* Y    = (const float*)d_in[1];   // [512][128][1024]
  const float* eWih = (const float*)d_in[2];   // [2][1024][1024]
  const float* eWhh = (const float*)d_in[3];
  const float* ebih = (const float*)d_in[4];   // [2][1024]
  const float* ebhh = (const float*)d_in[5];
  const float* dWih = (const float*)d_in[6];
  const float* dWhh = (const float*)d_in[7];
  const float* dbih = (const float*)d_in[8];
  const float* dbhh = (const float*)d_in[9];
  const float* linW = (const float*)d_in[10];  // [1024][1024]
  const float* linb = (const float*)d_in[11];  // [1024]

  // workspace layout
  char* ws = (char*)d_ws;
  unsigned* flags = (unsigned*)ws;                                // 4KB
  f16* h0b  = (f16*)(ws + 4096);                                  // 3*128*1024*2
  f16* h1b  = (f16*)(ws + 4096 + 786432);
  f16* pre0 = (f16*)(ws + 2097152);                               // 128MB
  f16* tops = (f16*)(ws + 2097152 + 134217728);                   // 128MB

  const size_t LAYER1 = 1024 * 1024;
  const int M = 512 * 128;

  hipFuncSetAttribute((const void*)rnn_phase,
                      hipFuncAttributeMaxDynamicSharedMemorySize, RNN_LDS);

  // zero flags + hidden state
  hipMemsetAsync(d_ws, 0, 4096 + 2 * 786432, stream);

  dim3 ggrid(8, 512);

  // 1) encoder layer-0 input GEMM
  gemm_bias<float, true><<<ggrid, 256, 0, stream>>>(
      X, X, 1 << 30, eWih, ebih, ebhh, pre0, M, 1024, 1024);

  // 2) encoder recurrence
  rnn_phase<<<256, 256, RNN_LDS, stream>>>(
      pre0, h0b, h1b, flags,
      eWhh, eWih + LAYER1, eWhh + LAYER1, ebih + 1024, ebhh + 1024,
      nullptr, 0);

  // 3) decoder layer-0 input GEMM
  gemm_bias<float, true><<<ggrid, 256, 0, stream>>>(
      X + (size_t)512 * 128 * 1024, Y, 128, dWih, dbih, dbhh, pre0, M, 1024, 1024);

  // reset flags for decoder phase (hidden state carries over)
  hipMemsetAsync(d_ws, 0, 4096, stream);

  // 4) decoder recurrence (writes tops)
  rnn_phase<<<256, 256, RNN_LDS, stream>>>(
      pre0, h0b, h1b, flags,
      dWhh, dWih + LAYER1, dWhh + LAYER1, dbih + 1024, dbhh + 1024,
      tops, 513);

  // 5) final linear -> logits (f32) into d_out
  gemm_bias<f16, false><<<ggrid, 256, 0, stream>>>(
      tops, tops, 1 << 30, linW, linb, nullptr, d_out, M, 1024, 1024);

  // 6) in-place log_softmax
  logsoftmax_rows<<<M, 256, 0, stream>>>((float*)d_out);
}

// Round 3
// 9313.593 us; speedup vs baseline: 1.7861x; 1.3943x over previous
//
#include <hip/hip_runtime.h>

// ---------------------------------------------------------------------------
// RNN seq2seq (2-layer Elman, enc 512 + dec 512, B=128, H=D=1024) + linear +
// log_softmax.
//
//   1) gemm_bias: pre0_enc = X@Wih0_e^T + b          (f16)
//   2) rnn_phase (persistent, 256 WG = 1/CU): skewed pipeline, 1 barrier/step
//   3) gemm_bias: pre0_dec from [X[512], Y[0..510]]
//   4) rnn_phase decoder, writes tops (f16)
//   5) gemm_bias: logits = tops@lin_W^T + lin_b  (f32 -> d_out)
//   6) logsoftmax_rows in-place on d_out
//
// Round-3 rnn_phase:
//  - weight slices live in VGPRs (96/wave), loaded once per phase: no weight
//    LDS reads at all (kills the 6.9e7 bank-conflict cycles).
//  - h-state loads: 32x inline-asm global_load_dwordx4 sc0 per lane, single
//    s_waitcnt vmcnt(0) + sched_barrier, then a pure 48-MFMA burst.
//  - broadcast via XCD-local L2: consumer loads sc0 (hit L2), producer stores
//    sc1 (write-through to MALL). Staleness defeated by a 16-deep h ring +
//    buffer_inv every 4 steps (window 4 << reuse distance 16); the inv at
//    s_loc==0 also clears stale lines from the previous graph replay.
// ---------------------------------------------------------------------------

typedef _Float16 f16;
typedef _Float16 f16x8 __attribute__((ext_vector_type(8)));
typedef _Float16 f16x4 __attribute__((ext_vector_type(4)));
typedef float    f32x4 __attribute__((ext_vector_type(4)));
typedef unsigned long long u64;

#define MFMA16(a, b, c) __builtin_amdgcn_mfma_f32_16x16x32_f16((a), (b), (c), 0, 0, 0)

__device__ __forceinline__ f32x4 zero4() {
  f32x4 v; v[0] = 0.f; v[1] = 0.f; v[2] = 0.f; v[3] = 0.f; return v;
}

__device__ __forceinline__ f16x8 cvt8(const float* __restrict__ p) {
  float4 a = *(const float4*)p;
  float4 b = *(const float4*)(p + 4);
  f16x8 r;
  r[0] = (f16)a.x; r[1] = (f16)a.y; r[2] = (f16)a.z; r[3] = (f16)a.w;
  r[4] = (f16)b.x; r[5] = (f16)b.y; r[6] = (f16)b.z; r[7] = (f16)b.w;
  return r;
}

// --- device-coherent (MALL) 8B load/store for h hand-off and flags --------
__device__ __forceinline__ f16x4 ld_h4(const f16* p) {
  u64 v = __hip_atomic_load((const u64*)p, __ATOMIC_RELAXED, __HIP_MEMORY_SCOPE_AGENT);
  return __builtin_bit_cast(f16x4, v);
}
__device__ __forceinline__ void st_h4(f16* p, f16x4 v) {
  __hip_atomic_store((u64*)p, __builtin_bit_cast(u64, v), __ATOMIC_RELAXED, __HIP_MEMORY_SCOPE_AGENT);
}

// ---------------------------------------------------------------------------
// GEMM: out[m][n] = sum_k A[m][k] * B[n][k] + bias1[n] (+ bias2[n])
// ---------------------------------------------------------------------------
template <typename AT, bool OUT_F16>
__global__ __launch_bounds__(256)
void gemm_bias(const AT* __restrict__ A1, const AT* __restrict__ A2, int rowSplit,
               const float* __restrict__ B, const float* __restrict__ bias1,
               const float* __restrict__ bias2, void* __restrict__ outp,
               int M, int N, int K)
{
  __shared__ f16 Ash[128 * 64];
  __shared__ f16 Bsh[128 * 64];
  const int t = threadIdx.x;
  const int w = t >> 6, l = t & 63;
  const int wm = w >> 1, wn = w & 1;
  const int lrow = l & 15, lk8 = (l >> 4) * 8;
  const int m0 = blockIdx.y * 128, n0 = blockIdx.x * 128;
  const int sr = t >> 3;
  const int skf = (t & 7) * 8;

  f32x4 acc[4][4];
#pragma unroll
  for (int i = 0; i < 4; ++i)
#pragma unroll
    for (int j = 0; j < 4; ++j) acc[i][j] = zero4();

  f16x8 ar[4], br[4];

  auto loadA = [&](int r, int k) -> f16x8 {
    const int row = m0 + r;
    if constexpr (sizeof(AT) == 4) {
      const float* src = (row < rowSplit) ? ((const float*)A1 + (size_t)row * K)
                                          : ((const float*)A2 + (size_t)(row - rowSplit) * K);
      return cvt8(src + k);
    } else {
      const f16* src = (row < rowSplit) ? ((const f16*)A1 + (size_t)row * K)
                                        : ((const f16*)A2 + (size_t)(row - rowSplit) * K);
      return *(const f16x8*)(src + k);
    }
  };
  auto loadB = [&](int r, int k) -> f16x8 {
    return cvt8(B + (size_t)(n0 + r) * K + k);
  };

#pragma unroll
  for (int s = 0; s < 4; ++s) { ar[s] = loadA(s * 32 + sr, skf); br[s] = loadB(s * 32 + sr, skf); }

  const int nkt = K >> 6;
  for (int kt = 0; kt < nkt; ++kt) {
#pragma unroll
    for (int s = 0; s < 4; ++s) {
      const int r = s * 32 + sr;
      const int di = r * 64 + (skf ^ ((r & 7) << 3));
      *(f16x8*)(Ash + di) = ar[s];
      *(f16x8*)(Bsh + di) = br[s];
    }
    __syncthreads();
    if (kt + 1 < nkt) {
      const int k0 = (kt + 1) << 6;
#pragma unroll
      for (int s = 0; s < 4; ++s) { ar[s] = loadA(s * 32 + sr, k0 + skf); br[s] = loadB(s * 32 + sr, k0 + skf); }
    }
#pragma unroll
    for (int ks = 0; ks < 2; ++ks) {
      const int kb = ks * 32 + lk8;
      f16x8 af[4], bf[4];
#pragma unroll
      for (int mt = 0; mt < 4; ++mt) {
        const int r = wm * 64 + mt * 16 + lrow;
        af[mt] = *(const f16x8*)(Ash + r * 64 + (kb ^ ((r & 7) << 3)));
      }
#pragma unroll
      for (int nt = 0; nt < 4; ++nt) {
        const int r = wn * 64 + nt * 16 + lrow;
        bf[nt] = *(const f16x8*)(Bsh + r * 64 + (kb ^ ((r & 7) << 3)));
      }
#pragma unroll
      for (int mt = 0; mt < 4; ++mt)
#pragma unroll
        for (int nt = 0; nt < 4; ++nt)
          acc[mt][nt] = MFMA16(af[mt], bf[nt], acc[mt][nt]);
    }
    __syncthreads();
  }

#pragma unroll
  for (int nt = 0; nt < 4; ++nt) {
    const int col = n0 + wn * 64 + nt * 16 + lrow;
    const float bv = bias1[col] + (bias2 ? bias2[col] : 0.f);
#pragma unroll
    for (int mt = 0; mt < 4; ++mt) {
#pragma unroll
      for (int r = 0; r < 4; ++r) {
        const int row = m0 + wm * 64 + mt * 16 + (l >> 4) * 4 + r;
        const float v = acc[mt][nt][r] + bv;
        if constexpr (OUT_F16) ((f16*)outp)[(size_t)row * N + col] = (f16)v;
        else                   ((float*)outp)[(size_t)row * N + col] = v;
      }
    }
  }
}

// ---------------------------------------------------------------------------
// Persistent RNN phase. 256 blocks x 256 threads, 1 block/CU (VGPR-limited).
// Block bid: group g = bid&3 (batch rows g*32..+31), slice = bid>>2 (out cols
// [slice*16,+16)). Each wave owns a K-quarter (kw = w*256) of all three
// weight slices, held in 96 VGPRs for the whole phase.
// Step s: h0[s] = tanh(pre0[s] + h0[s-1]@Whh0^T),
//         h1[s-1] = tanh(h0[s-1]@Wih1^T + h1[s-2]@Whh1^T + b1).
// h state: 16-deep ring per layer (f16, [16][128][1024]).
//   h0 of step t -> slot t%16 ; h1 of step t -> slot t%16.
//   At loop iter s: R0=(s+15)%16 W0=s%16 ; R1=(s+14)%16 W1=(s+15)%16.
// ---------------------------------------------------------------------------
__global__ __launch_bounds__(256, 1)
void rnn_phase(const f16* __restrict__ pre0,          // [512][128][1024]
               f16* __restrict__ h0b,                 // [16][128][1024]
               f16* __restrict__ h1b,                 // [16][128][1024]
               unsigned* flags,                       // [256] per-block step flags
               const float* __restrict__ Whh0, const float* __restrict__ Wih1,
               const float* __restrict__ Whh1, const float* __restrict__ bih1,
               const float* __restrict__ bhh1,
               f16* __restrict__ tops,                // [512][128][1024] or null
               int s_base)
{
  __shared__ float pbuf[8 * 32 * 20];    // [4 waves][2 parts][32 rows][20] f32

  const int t = threadIdx.x;
  const int w = t >> 6, l = t & 63;
  const int lrow = l & 15, lk8 = (l >> 4) * 8;
  const int bid = blockIdx.x;
  const int g = bid & 3;
  const int rbase = g * 32;
  const int c0 = (bid >> 2) * 16;
  const bool is_dec = (s_base != 0);
  const int kw = w * 256;                // wave K-quarter (f16 elements)

  // ---- load weight slices into registers (once per phase) ----
  f16x8 wv0[8], wv1[8], wv2[8];
  {
    const size_t wr = (size_t)(c0 + lrow) * 1024;
#pragma unroll
    for (int j = 0; j < 8; ++j) {
      const int k = kw + j * 32 + lk8;
      wv0[j] = cvt8(Whh0 + wr + k);
      wv1[j] = cvt8(Wih1 + wr + k);
      wv2[j] = cvt8(Whh1 + wr + k);
    }
  }

  // epilogue thread mapping: 128 threads per part, 4 outputs each
  const int ep_p = t >> 7;             // 0: h0 part, 1: h1 part
  const int ep_r = (t >> 2) & 31;      // local row 0..31
  const int ep_c = (t & 3) * 4;        // local col chunk
  float b1v[4];
#pragma unroll
  for (int i = 0; i < 4; ++i) b1v[i] = bih1[c0 + ep_c + i] + bhh1[c0 + ep_c + i];

  for (int s_loc = 0; s_loc <= 512; ++s_loc) {
    const int s = s_base + s_loc;

    // periodic L2 invalidate: bounds sc0-load staleness to 4 steps
    // (ring reuse distance is 16). s_loc==0 also clears the previous
    // graph-replay's lines.
    if ((s_loc & 3) == 0) {
      asm volatile("buffer_inv" ::: "memory");
      asm volatile("s_waitcnt vmcnt(0)" ::: "memory");
    }

    const int R0 = (s + 15) & 15, Wr0 = s & 15;
    const int R1 = (s + 14) & 15, Wr1 = (s + 15) & 15;
    const f16* h0p = h0b + (size_t)R0 * 131072;
    const f16* h1p = h1b + (size_t)R1 * 131072;
    f16* h0w = h0b + (size_t)Wr0 * 131072;
    f16* h1w = h1b + (size_t)Wr1 * 131072;
    const bool cmp_h0 = (s_loc < 512);
    const bool h1_copy = (is_dec && s_loc == 0);
    const bool cmp_h1 = !((!is_dec && s_loc == 0) || h1_copy);

    // early pre0 load (plain cached; drained by the big vmcnt(0) below)
    f16x4 pre4;
    pre4[0] = (f16)0.f; pre4[1] = (f16)0.f; pre4[2] = (f16)0.f; pre4[3] = (f16)0.f;
    if (ep_p == 0 && cmp_h0)
      pre4 = *(const f16x4*)(pre0 + ((size_t)s_loc * 128 + rbase + ep_r) * 1024 + c0 + ep_c);

    // ---- issue all 32 h-state loads (sc0: bypass L1, served by XCD L2) ----
    f16x8 A0[8], A1[8], C0[8], C1[8];
    const f16* a0p = h0p + (size_t)(rbase + lrow) * 1024 + kw + lk8;
    const f16* a1p = a0p + 16 * 1024;
    const f16* c0p = h1p + (size_t)(rbase + lrow) * 1024 + kw + lk8;
    const f16* c1p = c0p + 16 * 1024;
#pragma unroll
    for (int j = 0; j < 8; ++j) {
      asm volatile("global_load_dwordx4 %0, %1, off sc0" : "=v"(A0[j]) : "v"(a0p + j * 32));
      asm volatile("global_load_dwordx4 %0, %1, off sc0" : "=v"(A1[j]) : "v"(a1p + j * 32));
      asm volatile("global_load_dwordx4 %0, %1, off sc0" : "=v"(C0[j]) : "v"(c0p + j * 32));
      asm volatile("global_load_dwordx4 %0, %1, off sc0" : "=v"(C1[j]) : "v"(c1p + j * 32));
    }

    f32x4 acc0[2], acc1[2];
    acc0[0] = zero4(); acc0[1] = zero4(); acc1[0] = zero4(); acc1[1] = zero4();

    asm volatile("s_waitcnt vmcnt(0)" ::: "memory");
    __builtin_amdgcn_sched_barrier(0);

    // ---- pure MFMA burst: 48 MFMAs, register A and register B ----
#pragma unroll
    for (int j = 0; j < 8; ++j) {
      acc0[0] = MFMA16(A0[j], wv0[j], acc0[0]);
      acc0[1] = MFMA16(A1[j], wv0[j], acc0[1]);
      acc1[0] = MFMA16(A0[j], wv1[j], acc1[0]);
      acc1[1] = MFMA16(A1[j], wv1[j], acc1[1]);
      acc1[0] = MFMA16(C0[j], wv2[j], acc1[0]);
      acc1[1] = MFMA16(C1[j], wv2[j], acc1[1]);
    }

    // partials -> LDS (stride 20: conflict-free scalar writes, aligned reads)
#pragma unroll
    for (int mt = 0; mt < 2; ++mt)
#pragma unroll
      for (int r = 0; r < 4; ++r) {
        const int row = mt * 16 + (l >> 4) * 4 + r;
        pbuf[((w * 2 + 0) * 32 + row) * 20 + lrow] = acc0[mt][r];
        pbuf[((w * 2 + 1) * 32 + row) * 20 + lrow] = acc1[mt][r];
      }
    __syncthreads();

    // reduce over 4 waves + activation + device-coherent store
    if (ep_p == 0) {
      if (cmp_h0) {
        f32x4 sum = zero4();
#pragma unroll
        for (int ww = 0; ww < 4; ++ww)
          sum += *(const f32x4*)(pbuf + ((ww * 2 + 0) * 32 + ep_r) * 20 + ep_c);
        f16x4 o;
#pragma unroll
        for (int i = 0; i < 4; ++i) o[i] = (f16)tanhf(sum[i] + (float)pre4[i]);
        st_h4(h0w + (size_t)(rbase + ep_r) * 1024 + c0 + ep_c, o);
      } else {                          // drain step: carry h0[511] forward
        f16x4 v = ld_h4(h0p + (size_t)(rbase + ep_r) * 1024 + c0 + ep_c);
        st_h4(h0w + (size_t)(rbase + ep_r) * 1024 + c0 + ep_c, v);
      }
    } else {
      if (cmp_h1) {
        f32x4 sum = zero4();
#pragma unroll
        for (int ww = 0; ww < 4; ++ww)
          sum += *(const f32x4*)(pbuf + ((ww * 2 + 1) * 32 + ep_r) * 20 + ep_c);
        f16x4 o;
#pragma unroll
        for (int i = 0; i < 4; ++i) o[i] = (f16)tanhf(sum[i] + b1v[i]);
        st_h4(h1w + (size_t)(rbase + ep_r) * 1024 + c0 + ep_c, o);
        if (tops && s_loc >= 1)
          *(f16x4*)(tops + ((size_t)(s_loc - 1) * 128 + rbase + ep_r) * 1024 + c0 + ep_c) = o;
      } else if (h1_copy) {             // dec fill step: carry h1_enc[511]
        f16x4 v = ld_h4(h1p + (size_t)(rbase + ep_r) * 1024 + c0 + ep_c);
        st_h4(h1w + (size_t)(rbase + ep_r) * 1024 + c0 + ep_c, v);
      }
    }
    __syncthreads();                    // all waves drain vmcnt before barrier

    if (s_loc == 512) break;            // no in-kernel consumer of last step

    // ---- fence-free group barrier through the MALL ----
    asm volatile("s_waitcnt vmcnt(0)" ::: "memory");
    if (t == 0)
      __hip_atomic_store(flags + bid, (unsigned)(s_loc + 1),
                         __ATOMIC_RELAXED, __HIP_MEMORY_SCOPE_AGENT);
    if (w == 0) {                       // wave0: poll my group's 64 flags
      unsigned* fp = flags + 4 * l + g;
      const unsigned tgt = (unsigned)(s_loc + 1);
      for (;;) {
        unsigned v = __hip_atomic_load(fp, __ATOMIC_RELAXED, __HIP_MEMORY_SCOPE_AGENT);
        if (__all((int)(v >= tgt))) break;
        __builtin_amdgcn_s_sleep(2);
      }
    }
    __syncthreads();
  }
}

// ---------------------------------------------------------------------------
// In-place log_softmax over rows of 1024 f32.
// ---------------------------------------------------------------------------
__global__ __launch_bounds__(256)
void logsoftmax_rows(float* __restrict__ x)
{
  const int row = blockIdx.x;
  const int t = threadIdx.x;
  float* p = x + (size_t)row * 1024;
  float4 v = ((float4*)p)[t];
  float m = fmaxf(fmaxf(v.x, v.y), fmaxf(v.z, v.w));
#pragma unroll
  for (int off = 32; off >= 1; off >>= 1) m = fmaxf(m, __shfl_xor(m, off));
  __shared__ float red[4];
  __shared__ float red2[4];
  const int w = t >> 6;
  if ((t & 63) == 0) red[w] = m;
  __syncthreads();
  m = fmaxf(fmaxf(red[0], red[1]), fmaxf(red[2], red[3]));
  float s = __expf(v.x - m) + __expf(v.y - m) + __expf(v.z - m) + __expf(v.w - m);
#pragma unroll
  for (int off = 32; off >= 1; off >>= 1) s += __shfl_xor(s, off);
  if ((t & 63) == 0) red2[w] = s;
  __syncthreads();
  s = red2[0] + red2[1] + red2[2] + red2[3];
  const float lse = m + __logf(s);
  v.x -= lse; v.y -= lse; v.z -= lse; v.w -= lse;
  ((float4*)p)[t] = v;
}

// ---------------------------------------------------------------------------
extern "C" void kernel_launch(void* const* d_in, const int* in_sizes, int n_in,
                              void* d_out, int out_size, void* d_ws, size_t ws_size,
                              hipStream_t stream)
{
  (void)in_sizes; (void)n_in; (void)out_size; (void)ws_size;

  const float* X    = (const float*)d_in[0];   // [513][128][1024]
  const float* Y    = (const float*)d_in[1];   // [512][128][1024]
  const float* eWih = (const float*)d_in[2];   // [2][1024][1024]
  const float* eWhh = (const float*)d_in[3];
  const float* ebih = (const float*)d_in[4];   // [2][1024]
  const float* ebhh = (const float*)d_in[5];
  const float* dWih = (const float*)d_in[6];
  const float* dWhh = (const float*)d_in[7];
  const float* dbih = (const float*)d_in[8];
  const float* dbhh = (const float*)d_in[9];
  const float* linW = (const float*)d_in[10];  // [1024][1024]
  const float* linb = (const float*)d_in[11];  // [1024]

  // workspace layout
  char* ws = (char*)d_ws;
  unsigned* flags = (unsigned*)ws;                                // 4KB
  f16* h0b  = (f16*)(ws + 65536);                                 // 16*256KB = 4MB
  f16* h1b  = (f16*)(ws + 65536 + (16u << 18));                   // 4MB
  f16* pre0 = (f16*)(ws + (16u << 20));                           // 128MB @ 16MB
  f16* tops = (f16*)(ws + (144u << 20));                          // 128MB @ 144MB

  const size_t LAYER1 = 1024 * 1024;
  const int M = 512 * 128;

  // zero flags + both h rings
  hipMemsetAsync(d_ws, 0, 65536 + (32u << 18), stream);

  dim3 ggrid(8, 512);

  // 1) encoder layer-0 input GEMM
  gemm_bias<float, true><<<ggrid, 256, 0, stream>>>(
      X, X, 1 << 30, eWih, ebih, ebhh, pre0, M, 1024, 1024);

  // 2) encoder recurrence
  rnn_phase<<<256, 256, 0, stream>>>(
      pre0, h0b, h1b, flags,
      eWhh, eWih + LAYER1, eWhh + LAYER1, ebih + 1024, ebhh + 1024,
      nullptr, 0);

  // 3) decoder layer-0 input GEMM
  gemm_bias<float, true><<<ggrid, 256, 0, stream>>>(
      X + (size_t)512 * 128 * 1024, Y, 128, dWih, dbih, dbhh, pre0, M, 1024, 1024);

  // reset flags for decoder phase (hidden state carries over)
  hipMemsetAsync(d_ws, 0, 4096, stream);

  // 4) decoder recurrence (writes tops)
  rnn_phase<<<256, 256, 0, stream>>>(
      pre0, h0b, h1b, flags,
      dWhh, dWih + LAYER1, dWhh + LAYER1, dbih + 1024, dbhh + 1024,
      tops, 513);

  // 5) final linear -> logits (f32) into d_out
  gemm_bias<f16, false><<<ggrid, 256, 0, stream>>>(
      tops, tops, 1 << 30, linW, linb, nullptr, d_out, M, 1024, 1024);

  // 6) in-place log_softmax
  logsoftmax_rows<<<M, 256, 0, stream>>>((float*)d_out);
}

// Round 4
// 7170.344 us; speedup vs baseline: 2.3199x; 1.2989x over previous
//
#include <hip/hip_runtime.h>

// ---------------------------------------------------------------------------
// RNN seq2seq (2-layer Elman, enc 512 + dec 512, B=128, H=D=1024) + linear +
// log_softmax.
//
//   1) gemm_bias: pre0_enc = X@Wih0_e^T + b          (f16)
//   2) rnn_phase (persistent, 128 WG): skewed pipeline, 1 barrier/step
//   3) gemm_bias: pre0_dec from [X[512], Y[0..510]]
//   4) rnn_phase decoder, writes tops (f16)
//   5) gemm_bias: logits = tops@lin_W^T + lin_b  (f32 -> d_out)
//   6) logsoftmax_rows in-place on d_out
//
// Round-4 rnn_phase: 128 blocks x 32 out-cols (halves aggregate L2 load
// traffic; per-block load volume = rows x K is independent of col count).
// Weights in VGPRs (192/wave). Per-block flag = global_atomic_add (RMW pins
// the flag line in the MALL; no cross-block RMW contention); wave0 polls its
// group's 32 contiguous flags. buffer_inv only from t==0 every 8 steps
// (staleness bound 8 < ring reuse distance 16).
// ---------------------------------------------------------------------------

typedef _Float16 f16;
typedef _Float16 f16x8 __attribute__((ext_vector_type(8)));
typedef _Float16 f16x4 __attribute__((ext_vector_type(4)));
typedef float    f32x4 __attribute__((ext_vector_type(4)));
typedef unsigned long long u64;

#define MFMA16(a, b, c) __builtin_amdgcn_mfma_f32_16x16x32_f16((a), (b), (c), 0, 0, 0)

__device__ __forceinline__ f32x4 zero4() {
  f32x4 v; v[0] = 0.f; v[1] = 0.f; v[2] = 0.f; v[3] = 0.f; return v;
}

__device__ __forceinline__ f16x8 cvt8(const float* __restrict__ p) {
  float4 a = *(const float4*)p;
  float4 b = *(const float4*)(p + 4);
  f16x8 r;
  r[0] = (f16)a.x; r[1] = (f16)a.y; r[2] = (f16)a.z; r[3] = (f16)a.w;
  r[4] = (f16)b.x; r[5] = (f16)b.y; r[6] = (f16)b.z; r[7] = (f16)b.w;
  return r;
}

__device__ __forceinline__ float fast_tanh(float x) {
  // tanh(x) = 1 - 2/(e^{2x}+1); e^{2x}=inf -> 1, e^{2x}=0 -> -1 (both correct)
  float e = __expf(2.f * x);
  return 1.f - 2.f / (e + 1.f);
}

// 16B device-visible store (sc0 sc1: bypass L1, write through L2)
__device__ __forceinline__ void st16_cc(f16* p, f16x8 v) {
  asm volatile("global_store_dwordx4 %0, %1, off sc0 sc1" :: "v"(p), "v"(v) : "memory");
}
// 16B load bypassing L1, served by XCD L2 (staleness bounded by inv cadence)
__device__ __forceinline__ f16x8 ld16_c(const f16* p) {
  f16x8 r;
  asm volatile("global_load_dwordx4 %0, %1, off sc0" : "=v"(r) : "v"(p));
  return r;
}

// ---------------------------------------------------------------------------
// GEMM: out[m][n] = sum_k A[m][k] * B[n][k] + bias1[n] (+ bias2[n])
// ---------------------------------------------------------------------------
template <typename AT, bool OUT_F16>
__global__ __launch_bounds__(256)
void gemm_bias(const AT* __restrict__ A1, const AT* __restrict__ A2, int rowSplit,
               const float* __restrict__ B, const float* __restrict__ bias1,
               const float* __restrict__ bias2, void* __restrict__ outp,
               int M, int N, int K)
{
  __shared__ f16 Ash[128 * 64];
  __shared__ f16 Bsh[128 * 64];
  const int t = threadIdx.x;
  const int w = t >> 6, l = t & 63;
  const int wm = w >> 1, wn = w & 1;
  const int lrow = l & 15, lk8 = (l >> 4) * 8;
  const int m0 = blockIdx.y * 128, n0 = blockIdx.x * 128;
  const int sr = t >> 3;
  const int skf = (t & 7) * 8;

  f32x4 acc[4][4];
#pragma unroll
  for (int i = 0; i < 4; ++i)
#pragma unroll
    for (int j = 0; j < 4; ++j) acc[i][j] = zero4();

  f16x8 ar[4], br[4];

  auto loadA = [&](int r, int k) -> f16x8 {
    const int row = m0 + r;
    if constexpr (sizeof(AT) == 4) {
      const float* src = (row < rowSplit) ? ((const float*)A1 + (size_t)row * K)
                                          : ((const float*)A2 + (size_t)(row - rowSplit) * K);
      return cvt8(src + k);
    } else {
      const f16* src = (row < rowSplit) ? ((const f16*)A1 + (size_t)row * K)
                                        : ((const f16*)A2 + (size_t)(row - rowSplit) * K);
      return *(const f16x8*)(src + k);
    }
  };
  auto loadB = [&](int r, int k) -> f16x8 {
    return cvt8(B + (size_t)(n0 + r) * K + k);
  };

#pragma unroll
  for (int s = 0; s < 4; ++s) { ar[s] = loadA(s * 32 + sr, skf); br[s] = loadB(s * 32 + sr, skf); }

  const int nkt = K >> 6;
  for (int kt = 0; kt < nkt; ++kt) {
#pragma unroll
    for (int s = 0; s < 4; ++s) {
      const int r = s * 32 + sr;
      const int di = r * 64 + (skf ^ ((r & 7) << 3));
      *(f16x8*)(Ash + di) = ar[s];
      *(f16x8*)(Bsh + di) = br[s];
    }
    __syncthreads();
    if (kt + 1 < nkt) {
      const int k0 = (kt + 1) << 6;
#pragma unroll
      for (int s = 0; s < 4; ++s) { ar[s] = loadA(s * 32 + sr, k0 + skf); br[s] = loadB(s * 32 + sr, k0 + skf); }
    }
#pragma unroll
    for (int ks = 0; ks < 2; ++ks) {
      const int kb = ks * 32 + lk8;
      f16x8 af[4], bf[4];
#pragma unroll
      for (int mt = 0; mt < 4; ++mt) {
        const int r = wm * 64 + mt * 16 + lrow;
        af[mt] = *(const f16x8*)(Ash + r * 64 + (kb ^ ((r & 7) << 3)));
      }
#pragma unroll
      for (int nt = 0; nt < 4; ++nt) {
        const int r = wn * 64 + nt * 16 + lrow;
        bf[nt] = *(const f16x8*)(Bsh + r * 64 + (kb ^ ((r & 7) << 3)));
      }
#pragma unroll
      for (int mt = 0; mt < 4; ++mt)
#pragma unroll
        for (int nt = 0; nt < 4; ++nt)
          acc[mt][nt] = MFMA16(af[mt], bf[nt], acc[mt][nt]);
    }
    __syncthreads();
  }

#pragma unroll
  for (int nt = 0; nt < 4; ++nt) {
    const int col = n0 + wn * 64 + nt * 16 + lrow;
    const float bv = bias1[col] + (bias2 ? bias2[col] : 0.f);
#pragma unroll
    for (int mt = 0; mt < 4; ++mt) {
#pragma unroll
      for (int r = 0; r < 4; ++r) {
        const int row = m0 + wm * 64 + mt * 16 + (l >> 4) * 4 + r;
        const float v = acc[mt][nt][r] + bv;
        if constexpr (OUT_F16) ((f16*)outp)[(size_t)row * N + col] = (f16)v;
        else                   ((float*)outp)[(size_t)row * N + col] = v;
      }
    }
  }
}

// ---------------------------------------------------------------------------
// Persistent RNN phase. 128 blocks x 256 threads.
// Block bid: group g = bid&3 (batch rows g*32..+31), slice = bid>>2 (0..31,
// out cols [slice*32, +32)). Each wave owns a K-quarter (kw = w*256) of all
// three weight slices (2 col-tiles x 8 k-slices x 3 = 192 VGPRs).
// Step s: h0[s] = tanh(pre0[s] + h0[s-1]@Whh0^T),
//         h1[s-1] = tanh(h0[s-1]@Wih1^T + h1[s-2]@Whh1^T + b1).
// h state: 16-deep rings [16][128][1024] f16.
//   At iter s: R0=(s+15)&15 W0=s&15 ; R1=(s+14)&15 W1=(s+15)&15.
// Producer stores sc0+sc1 (device-visible); consumer loads sc0 (XCD L2),
// staleness bounded by buffer_inv every 8 steps (< ring reuse distance 16).
// Barrier: per-block flag via global_atomic_add; wave0 polls group's 32 flags.
// ---------------------------------------------------------------------------
__global__ __launch_bounds__(256, 1)
void rnn_phase(const f16* __restrict__ pre0,          // [512][128][1024]
               f16* __restrict__ h0b,                 // [16][128][1024]
               f16* __restrict__ h1b,                 // [16][128][1024]
               unsigned* flags,                       // [128] per-block step flags
               const float* __restrict__ Whh0, const float* __restrict__ Wih1,
               const float* __restrict__ Whh1, const float* __restrict__ bih1,
               const float* __restrict__ bhh1,
               f16* __restrict__ tops,                // [512][128][1024] or null
               int s_base)
{
  __shared__ float pbuf[8][32][36];      // [wave*2+part][row][col(pad 36)]

  const int t = threadIdx.x;
  const int w = t >> 6, l = t & 63;
  const int lrow = l & 15, lk8 = (l >> 4) * 8;
  const int bid = blockIdx.x;
  const int g = bid & 3, slice = bid >> 2;
  const int rbase = g * 32, c0 = slice * 32;
  const bool is_dec = (s_base != 0);
  const int kw = w * 256;                // wave K-quarter (f16 elements)

  // ---- weight slices -> VGPRs (once per phase): [col-tile][k-slice] ----
  f16x8 wv0[2][8], wv1[2][8], wv2[2][8];
#pragma unroll
  for (int ct = 0; ct < 2; ++ct) {
    const size_t wr = (size_t)(c0 + ct * 16 + lrow) * 1024;
#pragma unroll
    for (int j = 0; j < 8; ++j) {
      const int k = kw + j * 32 + lk8;
      wv0[ct][j] = cvt8(Whh0 + wr + k);
      wv1[ct][j] = cvt8(Wih1 + wr + k);
      wv2[ct][j] = cvt8(Whh1 + wr + k);
    }
  }

  // epilogue mapping: 128 threads/part; thread: row = sub>>2, col chunk of 8
  const int ep_p = t >> 7;
  const int sub = t & 127;
  const int ep_r = sub >> 2;
  const int ep_cc = (sub & 3) * 8;
  float b1v[8];
#pragma unroll
  for (int i = 0; i < 8; ++i)
    b1v[i] = bih1[c0 + ep_cc + i] + bhh1[c0 + ep_cc + i];

  for (int s_loc = 0; s_loc <= 512; ++s_loc) {
    const int s = s_base + s_loc;

    // periodic consumer-L2 invalidate (t==0 only; L2-wide op). Cadence 8 <
    // ring reuse distance 16. s_loc==0 also clears cross-phase/replay lines.
    if ((s_loc & 7) == 0) {
      if (t == 0)
        asm volatile("buffer_inv\n\ts_waitcnt vmcnt(0)" ::: "memory");
      __syncthreads();
    }

    const int R0 = (s + 15) & 15, Wr0 = s & 15;
    const int R1 = (s + 14) & 15, Wr1 = (s + 15) & 15;
    const f16* h0p = h0b + (size_t)R0 * 131072;
    const f16* h1p = h1b + (size_t)R1 * 131072;
    f16* h0w = h0b + (size_t)Wr0 * 131072;
    f16* h1w = h1b + (size_t)Wr1 * 131072;
    const bool cmp_h0 = (s_loc < 512);
    const bool h1_copy = (is_dec && s_loc == 0);
    const bool cmp_h1 = !((!is_dec && s_loc == 0) || h1_copy);

    // ---- issue all 32 h-state loads (sc0: L1-bypass, XCD-L2 served) ----
    f16x8 A0[8], A1[8], C0[8], C1[8];
    const f16* a0p = h0p + (size_t)(rbase + lrow) * 1024 + kw + lk8;
    const f16* a1p = a0p + 16 * 1024;
    const f16* c0p = h1p + (size_t)(rbase + lrow) * 1024 + kw + lk8;
    const f16* c1p = c0p + 16 * 1024;
#pragma unroll
    for (int j = 0; j < 8; ++j) {
      asm volatile("global_load_dwordx4 %0, %1, off sc0" : "=v"(A0[j]) : "v"(a0p + j * 32));
      asm volatile("global_load_dwordx4 %0, %1, off sc0" : "=v"(A1[j]) : "v"(a1p + j * 32));
      asm volatile("global_load_dwordx4 %0, %1, off sc0" : "=v"(C0[j]) : "v"(c0p + j * 32));
      asm volatile("global_load_dwordx4 %0, %1, off sc0" : "=v"(C1[j]) : "v"(c1p + j * 32));
    }

    // early pre0 load (plain cached; drained by the big vmcnt(0) below)
    f16x8 pre8;
#pragma unroll
    for (int i = 0; i < 8; ++i) pre8[i] = (f16)0.f;
    if (ep_p == 0 && cmp_h0)
      pre8 = *(const f16x8*)(pre0 + ((size_t)s_loc * 128 + rbase + ep_r) * 1024 + c0 + ep_cc);

    f32x4 acc0[2][2], acc1[2][2];
#pragma unroll
    for (int a = 0; a < 2; ++a)
#pragma unroll
      for (int b = 0; b < 2; ++b) { acc0[a][b] = zero4(); acc1[a][b] = zero4(); }

    asm volatile("s_waitcnt vmcnt(0)" ::: "memory");
    __builtin_amdgcn_sched_barrier(0);

    // ---- pure MFMA burst: 96 MFMAs, register A and register B ----
#pragma unroll
    for (int j = 0; j < 8; ++j) {
#pragma unroll
      for (int ct = 0; ct < 2; ++ct) {
        acc0[0][ct] = MFMA16(A0[j], wv0[ct][j], acc0[0][ct]);
        acc0[1][ct] = MFMA16(A1[j], wv0[ct][j], acc0[1][ct]);
        acc1[0][ct] = MFMA16(A0[j], wv1[ct][j], acc1[0][ct]);
        acc1[1][ct] = MFMA16(A1[j], wv1[ct][j], acc1[1][ct]);
        acc1[0][ct] = MFMA16(C0[j], wv2[ct][j], acc1[0][ct]);
        acc1[1][ct] = MFMA16(C1[j], wv2[ct][j], acc1[1][ct]);
      }
    }

    // partials -> LDS ([w][part][row][col], stride 36: 2-way max = free)
#pragma unroll
    for (int rt = 0; rt < 2; ++rt)
#pragma unroll
      for (int ct = 0; ct < 2; ++ct)
#pragma unroll
        for (int r = 0; r < 4; ++r) {
          const int row = rt * 16 + (l >> 4) * 4 + r;
          pbuf[w * 2 + 0][row][ct * 16 + lrow] = acc0[rt][ct][r];
          pbuf[w * 2 + 1][row][ct * 16 + lrow] = acc1[rt][ct][r];
        }
    __syncthreads();

    // reduce over 4 waves + tanh + device-visible store
    if (ep_p == 0) {
      if (cmp_h0) {
        f32x4 sa = zero4(), sb = zero4();
#pragma unroll
        for (int ww = 0; ww < 4; ++ww) {
          sa += *(const f32x4*)&pbuf[ww * 2 + 0][ep_r][ep_cc];
          sb += *(const f32x4*)&pbuf[ww * 2 + 0][ep_r][ep_cc + 4];
        }
        f16x8 o;
#pragma unroll
        for (int i = 0; i < 4; ++i) o[i]     = (f16)fast_tanh(sa[i] + (float)pre8[i]);
#pragma unroll
        for (int i = 0; i < 4; ++i) o[4 + i] = (f16)fast_tanh(sb[i] + (float)pre8[4 + i]);
        st16_cc(h0w + (size_t)(rbase + ep_r) * 1024 + c0 + ep_cc, o);
      } else {                          // drain step: carry h0[511] forward
        f16x8 v = ld16_c(h0p + (size_t)(rbase + ep_r) * 1024 + c0 + ep_cc);
        asm volatile("s_waitcnt vmcnt(0)" ::: "memory");
        __builtin_amdgcn_sched_barrier(0);
        st16_cc(h0w + (size_t)(rbase + ep_r) * 1024 + c0 + ep_cc, v);
      }
    } else {
      if (cmp_h1) {
        f32x4 sa = zero4(), sb = zero4();
#pragma unroll
        for (int ww = 0; ww < 4; ++ww) {
          sa += *(const f32x4*)&pbuf[ww * 2 + 1][ep_r][ep_cc];
          sb += *(const f32x4*)&pbuf[ww * 2 + 1][ep_r][ep_cc + 4];
        }
        f16x8 o;
#pragma unroll
        for (int i = 0; i < 4; ++i) o[i]     = (f16)fast_tanh(sa[i] + b1v[i]);
#pragma unroll
        for (int i = 0; i < 4; ++i) o[4 + i] = (f16)fast_tanh(sb[i] + b1v[4 + i]);
        st16_cc(h1w + (size_t)(rbase + ep_r) * 1024 + c0 + ep_cc, o);
        if (tops && s_loc >= 1)
          *(f16x8*)(tops + ((size_t)(s_loc - 1) * 128 + rbase + ep_r) * 1024 + c0 + ep_cc) = o;
      } else if (h1_copy) {             // dec fill step: carry h1_enc[511]
        f16x8 v = ld16_c(h1p + (size_t)(rbase + ep_r) * 1024 + c0 + ep_cc);
        asm volatile("s_waitcnt vmcnt(0)" ::: "memory");
        __builtin_amdgcn_sched_barrier(0);
        st16_cc(h1w + (size_t)(rbase + ep_r) * 1024 + c0 + ep_cc, v);
      }
    }
    __syncthreads();                    // every wave drains its own stores

    if (s_loc == 512) break;            // no in-kernel consumer of last step

    // ---- group barrier: per-block flag add (MALL-pinned), wave0 polls ----
    if (t == 0)
      __hip_atomic_fetch_add(flags + (g << 5) + slice, 1u,
                             __ATOMIC_RELAXED, __HIP_MEMORY_SCOPE_AGENT);
    if (w == 0) {
      const unsigned tgt = (unsigned)(s_loc + 1);
      unsigned* fp = flags + (g << 5) + (l & 31);
      for (;;) {
        unsigned v = __hip_atomic_load(fp, __ATOMIC_RELAXED, __HIP_MEMORY_SCOPE_AGENT);
        if (__all((l < 32) ? (int)(v >= tgt) : 1)) break;
        __builtin_amdgcn_s_sleep(1);
      }
    }
    __syncthreads();
  }
}

// ---------------------------------------------------------------------------
// In-place log_softmax over rows of 1024 f32.
// ---------------------------------------------------------------------------
__global__ __launch_bounds__(256)
void logsoftmax_rows(float* __restrict__ x)
{
  const int row = blockIdx.x;
  const int t = threadIdx.x;
  float* p = x + (size_t)row * 1024;
  float4 v = ((float4*)p)[t];
  float m = fmaxf(fmaxf(v.x, v.y), fmaxf(v.z, v.w));
#pragma unroll
  for (int off = 32; off >= 1; off >>= 1) m = fmaxf(m, __shfl_xor(m, off));
  __shared__ float red[4];
  __shared__ float red2[4];
  const int w = t >> 6;
  if ((t & 63) == 0) red[w] = m;
  __syncthreads();
  m = fmaxf(fmaxf(red[0], red[1]), fmaxf(red[2], red[3]));
  float s = __expf(v.x - m) + __expf(v.y - m) + __expf(v.z - m) + __expf(v.w - m);
#pragma unroll
  for (int off = 32; off >= 1; off >>= 1) s += __shfl_xor(s, off);
  if ((t & 63) == 0) red2[w] = s;
  __syncthreads();
  s = red2[0] + red2[1] + red2[2] + red2[3];
  const float lse = m + __logf(s);
  v.x -= lse; v.y -= lse; v.z -= lse; v.w -= lse;
  ((float4*)p)[t] = v;
}

// ---------------------------------------------------------------------------
extern "C" void kernel_launch(void* const* d_in, const int* in_sizes, int n_in,
                              void* d_out, int out_size, void* d_ws, size_t ws_size,
                              hipStream_t stream)
{
  (void)in_sizes; (void)n_in; (void)out_size; (void)ws_size;

  const float* X    = (const float*)d_in[0];   // [513][128][1024]
  const float* Y    = (const float*)d_in[1];   // [512][128][1024]
  const float* eWih = (const float*)d_in[2];   // [2][1024][1024]
  const float* eWhh = (const float*)d_in[3];
  const float* ebih = (const float*)d_in[4];   // [2][1024]
  const float* ebhh = (const float*)d_in[5];
  const float* dWih = (const float*)d_in[6];
  const float* dWhh = (const float*)d_in[7];
  const float* dbih = (const float*)d_in[8];
  const float* dbhh = (const float*)d_in[9];
  const float* linW = (const float*)d_in[10];  // [1024][1024]
  const float* linb = (const float*)d_in[11];  // [1024]

  // workspace layout
  char* ws = (char*)d_ws;
  unsigned* flags = (unsigned*)ws;                                // 512B used
  f16* h0b  = (f16*)(ws + 65536);                                 // 16*256KB = 4MB
  f16* h1b  = (f16*)(ws + 65536 + (16u << 18));                   // 4MB
  f16* pre0 = (f16*)(ws + (16u << 20));                           // 128MB @ 16MB
  f16* tops = (f16*)(ws + (144u << 20));                          // 128MB @ 144MB

  const size_t LAYER1 = 1024 * 1024;
  const int M = 512 * 128;

  // zero flags + both h rings
  hipMemsetAsync(d_ws, 0, 65536 + (32u << 18), stream);

  dim3 ggrid(8, 512);

  // 1) encoder layer-0 input GEMM
  gemm_bias<float, true><<<ggrid, 256, 0, stream>>>(
      X, X, 1 << 30, eWih, ebih, ebhh, pre0, M, 1024, 1024);

  // 2) encoder recurrence
  rnn_phase<<<128, 256, 0, stream>>>(
      pre0, h0b, h1b, flags,
      eWhh, eWih + LAYER1, eWhh + LAYER1, ebih + 1024, ebhh + 1024,
      nullptr, 0);

  // 3) decoder layer-0 input GEMM
  gemm_bias<float, true><<<ggrid, 256, 0, stream>>>(
      X + (size_t)512 * 128 * 1024, Y, 128, dWih, dbih, dbhh, pre0, M, 1024, 1024);

  // reset flags for decoder phase (hidden state carries over)
  hipMemsetAsync(d_ws, 0, 4096, stream);

  // 4) decoder recurrence (writes tops)
  rnn_phase<<<128, 256, 0, stream>>>(
      pre0, h0b, h1b, flags,
      dWhh, dWih + LAYER1, dWhh + LAYER1, dbih + 1024, dbhh + 1024,
      tops, 513);

  // 5) final linear -> logits (f32) into d_out
  gemm_bias<f16, false><<<ggrid, 256, 0, stream>>>(
      tops, tops, 1 << 30, linW, linb, nullptr, d_out, M, 1024, 1024);

  // 6) in-place log_softmax
  logsoftmax_rows<<<M, 256, 0, stream>>>((float*)d_out);
}

// Round 5
// 5209.901 us; speedup vs baseline: 3.1929x; 1.3763x over previous
//
#include <hip/hip_runtime.h>

// ---------------------------------------------------------------------------
// RNN seq2seq (2-layer Elman, enc 512 + dec 512, B=128, H=D=1024) + linear +
// log_softmax.
//
//   1) gemm_bias: pre0_enc = X@Wih0_e^T + b          (f16)
//   2) rnn_phase (persistent, 256 WG): skewed pipeline, 1 barrier/step
//   3) gemm_bias: pre0_dec from [X[512], Y[0..510]]
//   4) rnn_phase decoder, writes tops (f16)
//   5) gemm_bias: logits = tops@lin_W^T + lin_b  (f32 -> d_out)
//   6) logsoftmax_rows in-place on d_out
//
// Round-5 rnn_phase: XCD-local groups. 256 blocks = 8 groups x 32 slices,
// group = bid&7 -> with round-robin block->XCD dispatch, a group's 32 blocks
// share one XCD L2. All h-state exchange and the flag barrier then run at
// L2 latency. Correctness is placement-INDEPENDENT:
//  - data: producer sc0+sc1 write-through (own L2 + MALL), consumer sc0
//    loads; 16-deep ring + buffer_inv every 8 steps bounds staleness.
//  - flags: single-writer sc0+sc1 stores, consumer sc0 polls with every-8th
//    agent-scope (MALL) load for guaranteed progress; within a phase flags
//    only increase (stale lines are stale-LOW = safe); cross-phase stale-HIGH
//    killed by step-0 buffer_inv + flag memset.
// ---------------------------------------------------------------------------

typedef _Float16 f16;
typedef _Float16 f16x8 __attribute__((ext_vector_type(8)));
typedef _Float16 f16x4 __attribute__((ext_vector_type(4)));
typedef float    f32x4 __attribute__((ext_vector_type(4)));
typedef unsigned long long u64;

#define MFMA16(a, b, c) __builtin_amdgcn_mfma_f32_16x16x32_f16((a), (b), (c), 0, 0, 0)

__device__ __forceinline__ f32x4 zero4() {
  f32x4 v; v[0] = 0.f; v[1] = 0.f; v[2] = 0.f; v[3] = 0.f; return v;
}

__device__ __forceinline__ f16x8 cvt8(const float* __restrict__ p) {
  float4 a = *(const float4*)p;
  float4 b = *(const float4*)(p + 4);
  f16x8 r;
  r[0] = (f16)a.x; r[1] = (f16)a.y; r[2] = (f16)a.z; r[3] = (f16)a.w;
  r[4] = (f16)b.x; r[5] = (f16)b.y; r[6] = (f16)b.z; r[7] = (f16)b.w;
  return r;
}

__device__ __forceinline__ float fast_tanh(float x) {
  float e = __expf(2.f * x);
  return 1.f - 2.f / (e + 1.f);
}

// 8B device-visible store (bypass L1, update L2, write through to MALL)
__device__ __forceinline__ void st8_cc(f16* p, f16x4 v) {
  asm volatile("global_store_dwordx2 %0, %1, off sc0 sc1" :: "v"(p), "v"(v) : "memory");
}
// 8B load bypassing L1, served by XCD L2 (staleness bounded by inv cadence)
__device__ __forceinline__ f16x4 ld8_c(const f16* p) {
  f16x4 r;
  asm volatile("global_load_dwordx2 %0, %1, off sc0" : "=v"(r) : "v"(p));
  return r;
}

// ---------------------------------------------------------------------------
// GEMM: out[m][n] = sum_k A[m][k] * B[n][k] + bias1[n] (+ bias2[n])
// ---------------------------------------------------------------------------
template <typename AT, bool OUT_F16>
__global__ __launch_bounds__(256)
void gemm_bias(const AT* __restrict__ A1, const AT* __restrict__ A2, int rowSplit,
               const float* __restrict__ B, const float* __restrict__ bias1,
               const float* __restrict__ bias2, void* __restrict__ outp,
               int M, int N, int K)
{
  __shared__ f16 Ash[128 * 64];
  __shared__ f16 Bsh[128 * 64];
  const int t = threadIdx.x;
  const int w = t >> 6, l = t & 63;
  const int wm = w >> 1, wn = w & 1;
  const int lrow = l & 15, lk8 = (l >> 4) * 8;
  const int m0 = blockIdx.y * 128, n0 = blockIdx.x * 128;
  const int sr = t >> 3;
  const int skf = (t & 7) * 8;

  f32x4 acc[4][4];
#pragma unroll
  for (int i = 0; i < 4; ++i)
#pragma unroll
    for (int j = 0; j < 4; ++j) acc[i][j] = zero4();

  f16x8 ar[4], br[4];

  auto loadA = [&](int r, int k) -> f16x8 {
    const int row = m0 + r;
    if constexpr (sizeof(AT) == 4) {
      const float* src = (row < rowSplit) ? ((const float*)A1 + (size_t)row * K)
                                          : ((const float*)A2 + (size_t)(row - rowSplit) * K);
      return cvt8(src + k);
    } else {
      const f16* src = (row < rowSplit) ? ((const f16*)A1 + (size_t)row * K)
                                        : ((const f16*)A2 + (size_t)(row - rowSplit) * K);
      return *(const f16x8*)(src + k);
    }
  };
  auto loadB = [&](int r, int k) -> f16x8 {
    return cvt8(B + (size_t)(n0 + r) * K + k);
  };

#pragma unroll
  for (int s = 0; s < 4; ++s) { ar[s] = loadA(s * 32 + sr, skf); br[s] = loadB(s * 32 + sr, skf); }

  const int nkt = K >> 6;
  for (int kt = 0; kt < nkt; ++kt) {
#pragma unroll
    for (int s = 0; s < 4; ++s) {
      const int r = s * 32 + sr;
      const int di = r * 64 + (skf ^ ((r & 7) << 3));
      *(f16x8*)(Ash + di) = ar[s];
      *(f16x8*)(Bsh + di) = br[s];
    }
    __syncthreads();
    if (kt + 1 < nkt) {
      const int k0 = (kt + 1) << 6;
#pragma unroll
      for (int s = 0; s < 4; ++s) { ar[s] = loadA(s * 32 + sr, k0 + skf); br[s] = loadB(s * 32 + sr, k0 + skf); }
    }
#pragma unroll
    for (int ks = 0; ks < 2; ++ks) {
      const int kb = ks * 32 + lk8;
      f16x8 af[4], bf[4];
#pragma unroll
      for (int mt = 0; mt < 4; ++mt) {
        const int r = wm * 64 + mt * 16 + lrow;
        af[mt] = *(const f16x8*)(Ash + r * 64 + (kb ^ ((r & 7) << 3)));
      }
#pragma unroll
      for (int nt = 0; nt < 4; ++nt) {
        const int r = wn * 64 + nt * 16 + lrow;
        bf[nt] = *(const f16x8*)(Bsh + r * 64 + (kb ^ ((r & 7) << 3)));
      }
#pragma unroll
      for (int mt = 0; mt < 4; ++mt)
#pragma unroll
        for (int nt = 0; nt < 4; ++nt)
          acc[mt][nt] = MFMA16(af[mt], bf[nt], acc[mt][nt]);
    }
    __syncthreads();
  }

#pragma unroll
  for (int nt = 0; nt < 4; ++nt) {
    const int col = n0 + wn * 64 + nt * 16 + lrow;
    const float bv = bias1[col] + (bias2 ? bias2[col] : 0.f);
#pragma unroll
    for (int mt = 0; mt < 4; ++mt) {
#pragma unroll
      for (int r = 0; r < 4; ++r) {
        const int row = m0 + wm * 64 + mt * 16 + (l >> 4) * 4 + r;
        const float v = acc[mt][nt][r] + bv;
        if constexpr (OUT_F16) ((f16*)outp)[(size_t)row * N + col] = (f16)v;
        else                   ((float*)outp)[(size_t)row * N + col] = v;
      }
    }
  }
}

// ---------------------------------------------------------------------------
// Persistent RNN phase. 256 blocks x 256 threads, 1 block/CU.
// Block bid: group g = bid&7 (batch rows g*16..+15; with round-robin
// dispatch all 32 blocks of a group share one XCD), slice = bid>>3 (out cols
// [slice*32,+32)). Each wave owns a K-quarter (kw=w*256) of all three weight
// slices (2 col-tiles x 8 k-slices x 3 = 192 VGPRs).
// Step s: h0[s] = tanh(pre0[s] + h0[s-1]@Whh0^T),
//         h1[s-1] = tanh(h0[s-1]@Wih1^T + h1[s-2]@Whh1^T + b1).
// h state: 16-deep rings [16][128][1024] f16.
//   At iter s: R0=(s+15)&15 W0=s&15 ; R1=(s+14)&15 W1=(s+15)&15.
// ---------------------------------------------------------------------------
__global__ __launch_bounds__(256, 1)
void rnn_phase(const f16* __restrict__ pre0,          // [512][128][1024]
               f16* __restrict__ h0b,                 // [16][128][1024]
               f16* __restrict__ h1b,                 // [16][128][1024]
               unsigned* flags,                       // [256] per-block step flags
               const float* __restrict__ Whh0, const float* __restrict__ Wih1,
               const float* __restrict__ Whh1, const float* __restrict__ bih1,
               const float* __restrict__ bhh1,
               f16* __restrict__ tops,                // [512][128][1024] or null
               int s_base)
{
  __shared__ float pbuf[8][16][36];      // [wave*2+part][row][col(pad 36)]

  const int t = threadIdx.x;
  const int w = t >> 6, l = t & 63;
  const int lrow = l & 15, lk8 = (l >> 4) * 8;
  const int bid = blockIdx.x;
  const int g = bid & 7, slice = bid >> 3;
  const int rbase = g * 16, c0 = slice * 32;
  const bool is_dec = (s_base != 0);
  const int kw = w * 256;                // wave K-quarter (f16 elements)

  // ---- weight slices -> VGPRs (once per phase): [col-tile][k-slice] ----
  f16x8 wv0[2][8], wv1[2][8], wv2[2][8];
#pragma unroll
  for (int ct = 0; ct < 2; ++ct) {
    const size_t wr = (size_t)(c0 + ct * 16 + lrow) * 1024;
#pragma unroll
    for (int j = 0; j < 8; ++j) {
      const int k = kw + j * 32 + lk8;
      wv0[ct][j] = cvt8(Whh0 + wr + k);
      wv1[ct][j] = cvt8(Wih1 + wr + k);
      wv2[ct][j] = cvt8(Whh1 + wr + k);
    }
  }

  // epilogue mapping: 128 threads/part; thread -> (row, 4-col chunk)
  const int ep_p = t >> 7;             // 0: h0, 1: h1
  const int sub = t & 127;
  const int ep_r = sub >> 3;           // 0..15
  const int ep_c = (sub & 7) * 4;      // 0..28
  float b1v[4];
#pragma unroll
  for (int i = 0; i < 4; ++i)
    b1v[i] = bih1[c0 + ep_c + i] + bhh1[c0 + ep_c + i];

  const int fidx = (g << 5) + slice;

  for (int s_loc = 0; s_loc <= 512; ++s_loc) {
    const int s = s_base + s_loc;

    // periodic own-L2 invalidate: bounds sc0 staleness to 8 steps (< ring
    // reuse distance 16); s_loc==0 also clears cross-phase/replay lines.
    if ((s_loc & 7) == 0) {
      if (t == 0)
        asm volatile("buffer_inv\n\ts_waitcnt vmcnt(0)" ::: "memory");
      __syncthreads();
    }

    const int R0 = (s + 15) & 15, Wr0 = s & 15;
    const int R1 = (s + 14) & 15, Wr1 = (s + 15) & 15;
    const f16* h0p = h0b + (size_t)R0 * 131072;
    const f16* h1p = h1b + (size_t)R1 * 131072;
    f16* h0w = h0b + (size_t)Wr0 * 131072;
    f16* h1w = h1b + (size_t)Wr1 * 131072;
    const bool cmp_h0 = (s_loc < 512);
    const bool h1_copy = (is_dec && s_loc == 0);
    const bool cmp_h1 = !((!is_dec && s_loc == 0) || h1_copy);

    // ---- issue all 16 h-state loads (sc0: L1-bypass, XCD-L2 served) ----
    f16x8 A[8], C[8];
    const f16* ap = h0p + (size_t)(rbase + lrow) * 1024 + kw + lk8;
    const f16* cp = h1p + (size_t)(rbase + lrow) * 1024 + kw + lk8;
#pragma unroll
    for (int j = 0; j < 8; ++j) {
      asm volatile("global_load_dwordx4 %0, %1, off sc0" : "=v"(A[j]) : "v"(ap + j * 32));
      asm volatile("global_load_dwordx4 %0, %1, off sc0" : "=v"(C[j]) : "v"(cp + j * 32));
    }

    // early pre0 load (plain cached; drained by the big vmcnt(0) below)
    f16x4 pre4;
#pragma unroll
    for (int i = 0; i < 4; ++i) pre4[i] = (f16)0.f;
    if (ep_p == 0 && cmp_h0)
      pre4 = *(const f16x4*)(pre0 + ((size_t)s_loc * 128 + rbase + ep_r) * 1024 + c0 + ep_c);

    f32x4 acc0[2], acc1[2];
    acc0[0] = zero4(); acc0[1] = zero4(); acc1[0] = zero4(); acc1[1] = zero4();

    asm volatile("s_waitcnt vmcnt(0)" ::: "memory");
    __builtin_amdgcn_sched_barrier(0);

    // ---- pure MFMA burst: 48 MFMAs, register A and register B ----
#pragma unroll
    for (int j = 0; j < 8; ++j) {
#pragma unroll
      for (int ct = 0; ct < 2; ++ct) {
        acc0[ct] = MFMA16(A[j], wv0[ct][j], acc0[ct]);
        acc1[ct] = MFMA16(A[j], wv1[ct][j], acc1[ct]);
        acc1[ct] = MFMA16(C[j], wv2[ct][j], acc1[ct]);
      }
    }

    // partials -> LDS
#pragma unroll
    for (int ct = 0; ct < 2; ++ct)
#pragma unroll
      for (int r = 0; r < 4; ++r) {
        const int row = (l >> 4) * 4 + r;
        pbuf[w * 2 + 0][row][ct * 16 + lrow] = acc0[ct][r];
        pbuf[w * 2 + 1][row][ct * 16 + lrow] = acc1[ct][r];
      }
    __syncthreads();

    // reduce over 4 waves + tanh + device-visible store
    if (ep_p == 0) {
      if (cmp_h0) {
        f32x4 sa = zero4();
#pragma unroll
        for (int ww = 0; ww < 4; ++ww)
          sa += *(const f32x4*)&pbuf[ww * 2 + 0][ep_r][ep_c];
        f16x4 o;
#pragma unroll
        for (int i = 0; i < 4; ++i) o[i] = (f16)fast_tanh(sa[i] + (float)pre4[i]);
        st8_cc(h0w + (size_t)(rbase + ep_r) * 1024 + c0 + ep_c, o);
      } else {                          // drain step: carry h0[511] forward
        f16x4 v = ld8_c(h0p + (size_t)(rbase + ep_r) * 1024 + c0 + ep_c);
        asm volatile("s_waitcnt vmcnt(0)" ::: "memory");
        __builtin_amdgcn_sched_barrier(0);
        st8_cc(h0w + (size_t)(rbase + ep_r) * 1024 + c0 + ep_c, v);
      }
    } else {
      if (cmp_h1) {
        f32x4 sa = zero4();
#pragma unroll
        for (int ww = 0; ww < 4; ++ww)
          sa += *(const f32x4*)&pbuf[ww * 2 + 1][ep_r][ep_c];
        f16x4 o;
#pragma unroll
        for (int i = 0; i < 4; ++i) o[i] = (f16)fast_tanh(sa[i] + b1v[i]);
        st8_cc(h1w + (size_t)(rbase + ep_r) * 1024 + c0 + ep_c, o);
        if (tops && s_loc >= 1)
          *(f16x4*)(tops + ((size_t)(s_loc - 1) * 128 + rbase + ep_r) * 1024 + c0 + ep_c) = o;
      } else if (h1_copy) {             // dec fill step: carry h1_enc[511]
        f16x4 v = ld8_c(h1p + (size_t)(rbase + ep_r) * 1024 + c0 + ep_c);
        asm volatile("s_waitcnt vmcnt(0)" ::: "memory");
        __builtin_amdgcn_sched_barrier(0);
        st8_cc(h1w + (size_t)(rbase + ep_r) * 1024 + c0 + ep_c, v);
      }
    }
    __syncthreads();                    // every wave drains its own stores

    if (s_loc == 512) break;            // no in-kernel consumer of last step

    // ---- group barrier: flag store (L2 + write-through), wave0 polls ----
    if (t == 0) {
      const unsigned val = (unsigned)(s_loc + 1);
      asm volatile("global_store_dword %0, %1, off sc0 sc1"
                   :: "v"(flags + fidx), "v"(val) : "memory");
    }
    if (w == 0) {
      const unsigned tgt = (unsigned)(s_loc + 1);
      unsigned* fp = flags + (g << 5) + (l & 31);
      int it = 0;
      for (;;) {
        unsigned v;
        if (((++it) & 7) == 0) {       // MALL-fresh: guarantees progress
          v = __hip_atomic_load(fp, __ATOMIC_RELAXED, __HIP_MEMORY_SCOPE_AGENT);
        } else {                       // fast path: own-XCD L2
          asm volatile("global_load_dword %0, %1, off sc0\n\ts_waitcnt vmcnt(0)"
                       : "=v"(v) : "v"(fp) : "memory");
        }
        if (__all((int)(v >= tgt))) break;
        __builtin_amdgcn_s_sleep(1);
      }
    }
    __syncthreads();
  }
}

// ---------------------------------------------------------------------------
// In-place log_softmax over rows of 1024 f32.
// ---------------------------------------------------------------------------
__global__ __launch_bounds__(256)
void logsoftmax_rows(float* __restrict__ x)
{
  const int row = blockIdx.x;
  const int t = threadIdx.x;
  float* p = x + (size_t)row * 1024;
  float4 v = ((float4*)p)[t];
  float m = fmaxf(fmaxf(v.x, v.y), fmaxf(v.z, v.w));
#pragma unroll
  for (int off = 32; off >= 1; off >>= 1) m = fmaxf(m, __shfl_xor(m, off));
  __shared__ float red[4];
  __shared__ float red2[4];
  const int w = t >> 6;
  if ((t & 63) == 0) red[w] = m;
  __syncthreads();
  m = fmaxf(fmaxf(red[0], red[1]), fmaxf(red[2], red[3]));
  float s = __expf(v.x - m) + __expf(v.y - m) + __expf(v.z - m) + __expf(v.w - m);
#pragma unroll
  for (int off = 32; off >= 1; off >>= 1) s += __shfl_xor(s, off);
  if ((t & 63) == 0) red2[w] = s;
  __syncthreads();
  s = red2[0] + red2[1] + red2[2] + red2[3];
  const float lse = m + __logf(s);
  v.x -= lse; v.y -= lse; v.z -= lse; v.w -= lse;
  ((float4*)p)[t] = v;
}

// ---------------------------------------------------------------------------
extern "C" void kernel_launch(void* const* d_in, const int* in_sizes, int n_in,
                              void* d_out, int out_size, void* d_ws, size_t ws_size,
                              hipStream_t stream)
{
  (void)in_sizes; (void)n_in; (void)out_size; (void)ws_size;

  const float* X    = (const float*)d_in[0];   // [513][128][1024]
  const float* Y    = (const float*)d_in[1];   // [512][128][1024]
  const float* eWih = (const float*)d_in[2];   // [2][1024][1024]
  const float* eWhh = (const float*)d_in[3];
  const float* ebih = (const float*)d_in[4];   // [2][1024]
  const float* ebhh = (const float*)d_in[5];
  const float* dWih = (const float*)d_in[6];
  const float* dWhh = (const float*)d_in[7];
  const float* dbih = (const float*)d_in[8];
  const float* dbhh = (const float*)d_in[9];
  const float* linW = (const float*)d_in[10];  // [1024][1024]
  const float* linb = (const float*)d_in[11];  // [1024]

  // workspace layout
  char* ws = (char*)d_ws;
  unsigned* flags = (unsigned*)ws;                                // 1KB used
  f16* h0b  = (f16*)(ws + 65536);                                 // 16*256KB = 4MB
  f16* h1b  = (f16*)(ws + 65536 + (16u << 18));                   // 4MB
  f16* pre0 = (f16*)(ws + (16u << 20));                           // 128MB @ 16MB
  f16* tops = (f16*)(ws + (144u << 20));                          // 128MB @ 144MB

  const size_t LAYER1 = 1024 * 1024;
  const int M = 512 * 128;

  // zero flags + both h rings
  hipMemsetAsync(d_ws, 0, 65536 + (32u << 18), stream);

  dim3 ggrid(8, 512);

  // 1) encoder layer-0 input GEMM
  gemm_bias<float, true><<<ggrid, 256, 0, stream>>>(
      X, X, 1 << 30, eWih, ebih, ebhh, pre0, M, 1024, 1024);

  // 2) encoder recurrence
  rnn_phase<<<256, 256, 0, stream>>>(
      pre0, h0b, h1b, flags,
      eWhh, eWih + LAYER1, eWhh + LAYER1, ebih + 1024, ebhh + 1024,
      nullptr, 0);

  // 3) decoder layer-0 input GEMM
  gemm_bias<float, true><<<ggrid, 256, 0, stream>>>(
      X + (size_t)512 * 128 * 1024, Y, 128, dWih, dbih, dbhh, pre0, M, 1024, 1024);

  // reset flags for decoder phase (hidden state carries over)
  hipMemsetAsync(d_ws, 0, 4096, stream);

  // 4) decoder recurrence (writes tops)
  rnn_phase<<<256, 256, 0, stream>>>(
      pre0, h0b, h1b, flags,
      dWhh, dWih + LAYER1, dWhh + LAYER1, dbih + 1024, dbhh + 1024,
      tops, 513);

  // 5) final linear -> logits (f32) into d_out
  gemm_bias<f16, false><<<ggrid, 256, 0, stream>>>(
      tops, tops, 1 << 30, linW, linb, nullptr, d_out, M, 1024, 1024);

  // 6) in-place log_softmax
  logsoftmax_rows<<<M, 256, 0, stream>>>((float*)d_out);
}